// Round 6
// baseline (604.320 us; speedup 1.0000x reference)
//
#include <hip/hip_runtime.h>
#include <hip/hip_bf16.h>

#define DIM 128
#define CAP 64       // padded CSR row capacity; in-deg ~Poisson(16), P(>=64) astronomically small
#define NBMAX 64     // max buckets (node-space / 2048)
#define BCAP 36864   // per-bucket edge capacity; mean ~32.7k, +22 sigma margin
#define CSPLIT 8     // sub-blocks per bucket for CSR/hist build (straggler fix, R13)

typedef __attribute__((ext_vector_type(8))) short bf16x8;
typedef __attribute__((ext_vector_type(4))) float f32x4;
typedef __bf16 bf16x2 __attribute__((ext_vector_type(2)));
union U16 { uint4 u; bf16x8 b; };
union UB { unsigned u; bf16x2 h; };

// ---- bf16 pack/unpack helpers (manual, RNE) ----
__device__ __forceinline__ unsigned short f2bf(float f) {
    unsigned u = __float_as_uint(f);
    unsigned r = (u + 0x7fffu + ((u >> 16) & 1u)) >> 16;
    return (unsigned short)r;
}
__device__ __forceinline__ unsigned pack2bf(float a, float b) {
    return (unsigned)f2bf(a) | ((unsigned)f2bf(b) << 16);
}
__device__ __forceinline__ float2 unpack2bf(unsigned v) {
    float2 r;
    r.x = __uint_as_float(v << 16);
    r.y = __uint_as_float(v & 0xffff0000u);
    return r;
}
// R14: native-__bf16 extraction + fmaf -> eligible for gfx950 v_fma_mix_f32_bf16.
__device__ __forceinline__ void accum8m(float* acc, uint4 v, float s) {
    UB w0, w1, w2, w3;
    w0.u = v.x; w1.u = v.y; w2.u = v.z; w3.u = v.w;
    acc[0] = fmaf((float)w0.h[0], s, acc[0]);
    acc[1] = fmaf((float)w0.h[1], s, acc[1]);
    acc[2] = fmaf((float)w1.h[0], s, acc[2]);
    acc[3] = fmaf((float)w1.h[1], s, acc[3]);
    acc[4] = fmaf((float)w2.h[0], s, acc[4]);
    acc[5] = fmaf((float)w2.h[1], s, acc[5]);
    acc[6] = fmaf((float)w3.h[0], s, acc[6]);
    acc[7] = fmaf((float)w3.h[1], s, acc[7]);
}

// ================= k_bin: bucket edges (R12-verified) + W1/W2/W3 bf16-T prepack tail ============
__global__ __launch_bounds__(256) void k_bin(const int* __restrict__ src,
                                             const int* __restrict__ dst, int E,
                                             unsigned* __restrict__ binD,
                                             unsigned short* __restrict__ binS,
                                             int* __restrict__ cntD,
                                             int* __restrict__ cntS, int NB, int binGrid,
                                             const float* __restrict__ W1,
                                             const float* __restrict__ W2,
                                             const float* __restrict__ W3,
                                             unsigned* __restrict__ wT1g,
                                             unsigned* __restrict__ wT2g,
                                             unsigned* __restrict__ wT3g) {
    __shared__ int hD[NBMAX], hS[NBMAX], bD[NBMAX], bS[NBMAX];
    int t = threadIdx.x;
    if ((int)blockIdx.x >= binGrid) {
        // ---------- W^T bf16 prepack: wTg[n*64+kp] = pack(W[2kp][n], W[2kp+1][n]) ----------
        int w = blockIdx.x - binGrid;
        const float* Wsrc = (w == 0) ? W1 : (w == 1) ? W2 : W3;
        unsigned* wTg = (w == 0) ? wT1g : (w == 1) ? wT2g : wT3g;
        int n = t >> 1;
        int kp0 = (t & 1) * 32;
#pragma unroll
        for (int i = 0; i < 32; i++) {
            int kp = kp0 + i;
            wTg[n * 64 + kp] = pack2bf(Wsrc[(2 * kp) * DIM + n], Wsrc[(2 * kp + 1) * DIM + n]);
        }
        return;
    }
    if (t < NB) { hD[t] = 0; hS[t] = 0; }
    __syncthreads();
    int e0 = blockIdx.x * 1024 + t * 4;
    int s[4], d[4];
    bool v[4];
#pragma unroll
    for (int i = 0; i < 4; i++) {
        v[i] = (e0 + i) < E;
        s[i] = 0; d[i] = 0;
        if (v[i]) { s[i] = src[e0 + i]; d[i] = dst[e0 + i]; }
    }
#pragma unroll
    for (int i = 0; i < 4; i++) {
        if (v[i]) {
            atomicAdd(&hD[d[i] >> 11], 1);
            atomicAdd(&hS[s[i] >> 11], 1);
        }
    }
    __syncthreads();
    if (t < NB) {
        bD[t] = atomicAdd(&cntD[t], hD[t]);
        bS[t] = atomicAdd(&cntS[t], hS[t]);
        hD[t] = 0; hS[t] = 0;
    }
    __syncthreads();
#pragma unroll
    for (int i = 0; i < 4; i++) {
        if (v[i]) {
            int bd = d[i] >> 11;
            int r = atomicAdd(&hD[bd], 1);
            int idx = bD[bd] + r;
            if (idx < BCAP)
                binD[bd * BCAP + idx] = ((unsigned)(d[i] & 2047) << 17) | (unsigned)s[i];
            int bs = s[i] >> 11;
            int r2 = atomicAdd(&hS[bs], 1);
            int idx2 = bS[bs] + r2;
            if (idx2 < BCAP) binS[bs * BCAP + idx2] = (unsigned short)(s[i] & 2047);
        }
    }
}

// ===== k_mega: CSR-from-buckets + src-histogram + layer-1 MFMA GEMM (fp32 X -> bf16 frags) ======
// [0, NB*CSPLIT): CSR sub-blocks; [NB*CSPLIT, 2*NB*CSPLIT): out_cnt histogram; rest: GEMM1.
// R17: GEMM1 epilogue writes xwb SLICE-MAJOR [8][N][8 unsigned] for XCD-local agg gathers.
__global__ __launch_bounds__(256) void k_mega(const unsigned* __restrict__ binD,
                                              const unsigned short* __restrict__ binS,
                                              const int* __restrict__ cntD,
                                              const int* __restrict__ cntS,
                                              int* __restrict__ in_cnt,
                                              int* __restrict__ out_cnt,
                                              int* __restrict__ csr_pad,
                                              const float* __restrict__ x,
                                              const unsigned* __restrict__ wT1g,
                                              unsigned* __restrict__ xwb, int N,
                                              int NB) {
    __shared__ __align__(16) char smem[34816];  // union: wT 34 KB | counters 16 KB
    int bid = blockIdx.x;
    int t = threadIdx.x;

    if (bid < NB * CSPLIT) {
        // ---------- CSR build: sub-block `sub` of bucket `b` ----------
        int b = bid / CSPLIT;
        int sub = bid - b * CSPLIT;
        int* h = (int*)smem;             // 2048 local counters
        int* bArr = ((int*)smem) + 2048; // 2048 global base offsets
        for (int j = t; j < 2048; j += 256) h[j] = 0;
        __syncthreads();
        int base = b << 11;
        int nE = cntD[b];
        if (nE > BCAP) nE = BCAP;
        int chunk = (nE + CSPLIT - 1) / CSPLIT;
        int i0 = sub * chunk;
        int i1 = i0 + chunk;
        if (i1 > nE) i1 = nE;
        const unsigned* bb = &binD[b * BCAP];
        for (int i = i0 + t * 4; i < i1; i += 1024) {
            unsigned e[4];
            int k = i1 - i;
            if (k > 4) k = 4;
#pragma unroll
            for (int j = 0; j < 4; j++)
                if (j < k) e[j] = bb[i + j];
#pragma unroll
            for (int j = 0; j < 4; j++)
                if (j < k) atomicAdd(&h[e[j] >> 17], 1);
        }
        __syncthreads();
        for (int j = t; j < 2048; j += 256) {
            int hv = h[j];
            bArr[j] = hv ? atomicAdd(&in_cnt[base + j], hv) : 0;
            h[j] = 0;
        }
        __syncthreads();
        for (int i = i0 + t * 4; i < i1; i += 1024) {
            unsigned e[4];
            int k = i1 - i;
            if (k > 4) k = 4;
#pragma unroll
            for (int j = 0; j < 4; j++)
                if (j < k) e[j] = bb[i + j];
#pragma unroll
            for (int j = 0; j < 4; j++)
                if (j < k) {
                    int dl = (int)(e[j] >> 17);
                    int pos = bArr[dl] + atomicAdd(&h[dl], 1);
                    if (pos < CAP)
                        csr_pad[(size_t)(base + dl) * CAP + pos] = (int)(e[j] & 0x1FFFFu);
                }
        }
        return;
    }
    if (bid < 2 * NB * CSPLIT) {
        // ---------- out-degree histogram: sub-block of bucket ----------
        int bb2 = bid - NB * CSPLIT;
        int b = bb2 / CSPLIT;
        int sub = bb2 - b * CSPLIT;
        int* hist = (int*)smem;
        for (int j = t; j < 2048; j += 256) hist[j] = 0;
        __syncthreads();
        int base = b << 11;
        int nE = cntS[b];
        if (nE > BCAP) nE = BCAP;
        int chunk = (nE + CSPLIT - 1) / CSPLIT;
        int i0 = sub * chunk;
        int i1 = i0 + chunk;
        if (i1 > nE) i1 = nE;
        const unsigned short* bs = &binS[b * BCAP];
        for (int i = i0 + t * 4; i < i1; i += 1024) {
            unsigned short e[4];
            int k = i1 - i;
            if (k > 4) k = 4;
#pragma unroll
            for (int j = 0; j < 4; j++)
                if (j < k) e[j] = bs[i + j];
#pragma unroll
            for (int j = 0; j < 4; j++)
                if (j < k) atomicAdd(&hist[(int)e[j]], 1);
        }
        __syncthreads();
        for (int j = t; j < 2048; j += 256) {
            int hv = hist[j];
            if (hv) atomicAdd(&out_cnt[base + j], hv);
        }
        return;
    }
    // ---------- GEMM1 via MFMA: xwb = bf16(X @ W1) (unscaled), slice-major write ----------
    int gb = bid - 2 * NB * CSPLIT;
    unsigned* wT = (unsigned*)smem;  // 128 rows x stride 68
#pragma unroll
    for (int i = 0; i < 8; i++) {
        int idx = t + i * 256;
        int row = idx >> 4;
        int col = idx & 15;
        *(uint4*)&wT[row * 68 + col * 4] = ((const uint4*)wT1g)[idx];
    }
    __syncthreads();
    int wave = t >> 6, lane = t & 63;
    int quad = lane >> 4, c = lane & 15;
    int m = gb * 64 + wave * 16 + c;
    bool mv = m < N;
    f32x4 acc[8];
#pragma unroll
    for (int i = 0; i < 8; i++) acc[i] = (f32x4){0.f, 0.f, 0.f, 0.f};

#pragma unroll
    for (int ks = 0; ks < 4; ks++) {
        U16 av;
        if (mv) {
            const float4* xr = (const float4*)&x[(size_t)m * DIM + ks * 32 + quad * 8];
            float4 f0 = xr[0], f1 = xr[1];
            av.u.x = pack2bf(f0.x, f0.y);
            av.u.y = pack2bf(f0.z, f0.w);
            av.u.z = pack2bf(f1.x, f1.y);
            av.u.w = pack2bf(f1.z, f1.w);
        } else {
            av.u = make_uint4(0, 0, 0, 0);
        }
#pragma unroll
        for (int cb = 0; cb < 8; cb++) {
            U16 bv;
            bv.u = *(const uint4*)&wT[(cb * 16 + c) * 68 + ks * 16 + quad * 4];
            acc[cb] = __builtin_amdgcn_mfma_f32_16x16x32_bf16(av.b, bv.b, acc[cb], 0, 0, 0);
        }
    }
    int rowBase = gb * 64 + wave * 16 + quad * 4;
#pragma unroll
    for (int r = 0; r < 4; r++) {
        int rowN = rowBase + r;
#pragma unroll
        for (int cb = 0; cb < 8; cb++) {
            float v = acc[cb][r];
            float vn = __shfl_xor(v, 1, 64);
            if (((c & 1) == 0) && rowN < N)
                xwb[(size_t)cb * N * 8 + (size_t)rowN * 8 + (c >> 1)] = pack2bf(v, vn);
        }
    }
}

// ---------------- k_nrm: precompute nsv[n] = rsqrt(out_deg+1) (R14; 400 KB, L2-resident) -------
__global__ __launch_bounds__(256) void k_nrm(const int* __restrict__ out_cnt,
                                             float* __restrict__ nsv, int N) {
    int i = (blockIdx.x * 256 + threadIdx.x) * 4;
    if (i + 3 < N) {
        int4 d = *(const int4*)&out_cnt[i];
        float4 r;
        r.x = rsqrtf((float)(d.x + 1));
        r.y = rsqrtf((float)(d.y + 1));
        r.z = rsqrtf((float)(d.z + 1));
        r.w = rsqrtf((float)(d.w + 1));
        *(float4*)&nsv[i] = r;
    } else {
        for (int j = i; j < N && j < i + 4; j++) nsv[j] = rsqrtf((float)(out_cnt[j] + 1));
    }
}

// ---------------- CSR aggregation, R17: XCD-sliced features -----------------------------------
// Input is SLICE-MAJOR [8][N][2 uint4]; slice f = blockIdx&7 -> fixed XCD (round-robin
// dispatch heuristic). Slice working set = N*32B = 3.2 MB < 4 MB per-XCD L2 -> gathers
// become L2-resident instead of 8x whole-buffer L3 streams (R15: FETCH 203MB = 8x25.6MB).
// Lane org: 8 lanes/node = 4 source-slots x 2 half-slices; no LDS; output NODE-MAJOR.
// MODE 0: layer-1 (unscaled src; per-source nsv[s], final *ndv)
// MODE 1: layers 2 (pre-scaled src; ndv in FMA)    MODE 2: layer 3 + gate partial dot
template <int MODE>
__device__ __forceinline__ void agg_body(const uint4* __restrict__ in4s,
                                         const int* __restrict__ in_cnt,
                                         const int* __restrict__ csr_pad,
                                         const float* __restrict__ nsv,
                                         const float* __restrict__ bias,
                                         uint4* __restrict__ out4,
                                         const float* __restrict__ Wp,
                                         float* __restrict__ wgp, int N) {
    int f = blockIdx.x & 7;
    int chunk = blockIdx.x >> 3;
    int t = threadIdx.x;
    int lane = t & 63;
    int node_g = lane >> 3;
    int slot = (lane >> 1) & 3;
    int c2 = lane & 1;
    int n0 = chunk * 32 + (t >> 6) * 8 + node_g;
    bool nv = n0 < N;
    int n = nv ? n0 : 0;
    int deg_true = in_cnt[n];
    int deg = deg_true > CAP ? CAP : deg_true;
    float ndv = rsqrtf((float)(deg_true + 1));
    const int* row = csr_pad + (size_t)n * CAP;
    const uint4* sl = in4s + (size_t)f * N * 2;

    float acc[8];
#pragma unroll
    for (int i = 0; i < 8; i++) acc[i] = 0.f;

    if (slot == 0) {
        float s0 = (MODE == 0) ? nsv[n] : ndv;
        accum8m(acc, sl[(size_t)n * 2 + c2], s0);  // self-loop
    }
    for (int p = 0; p < deg; p += 16) {
        int e0 = p + slot, e1 = p + 4 + slot, e2 = p + 8 + slot, e3 = p + 12 + slot;
        int i0 = row[e0], i1 = row[e1], i2 = row[e2], i3 = row[e3];
        bool v0 = e0 < deg, v1 = e1 < deg, v2 = e2 < deg, v3 = e3 < deg;
        int g0 = v0 ? i0 : n, g1 = v1 ? i1 : n, g2 = v2 ? i2 : n, g3 = v3 ? i3 : n;
        uint4 q0 = sl[(size_t)g0 * 2 + c2];
        uint4 q1 = sl[(size_t)g1 * 2 + c2];
        uint4 q2 = sl[(size_t)g2 * 2 + c2];
        uint4 q3 = sl[(size_t)g3 * 2 + c2];
        float s0, s1, s2, s3;
        if (MODE == 0) {
            float a0 = nsv[g0], a1 = nsv[g1], a2 = nsv[g2], a3 = nsv[g3];
            s0 = v0 ? a0 : 0.f; s1 = v1 ? a1 : 0.f; s2 = v2 ? a2 : 0.f; s3 = v3 ? a3 : 0.f;
        } else {
            s0 = v0 ? ndv : 0.f; s1 = v1 ? ndv : 0.f;
            s2 = v2 ? ndv : 0.f; s3 = v3 ? ndv : 0.f;
        }
        accum8m(acc, q0, s0);
        accum8m(acc, q1, s1);
        accum8m(acc, q2, s2);
        accum8m(acc, q3, s3);
    }
    // reduce across 4 source-slots (lane bits 1-2)
#pragma unroll
    for (int i = 0; i < 8; i++) {
        acc[i] += __shfl_xor(acc[i], 2, 64);
        acc[i] += __shfl_xor(acc[i], 4, 64);
    }
    float mul = (MODE == 0) ? ndv : 1.f;
    float4 b0 = ((const float4*)bias)[f * 4 + c2 * 2];
    float4 b1 = ((const float4*)bias)[f * 4 + c2 * 2 + 1];
    float o[8];
    o[0] = fmaxf(acc[0] * mul + b0.x, 0.f);
    o[1] = fmaxf(acc[1] * mul + b0.y, 0.f);
    o[2] = fmaxf(acc[2] * mul + b0.z, 0.f);
    o[3] = fmaxf(acc[3] * mul + b0.w, 0.f);
    o[4] = fmaxf(acc[4] * mul + b1.x, 0.f);
    o[5] = fmaxf(acc[5] * mul + b1.y, 0.f);
    o[6] = fmaxf(acc[6] * mul + b1.z, 0.f);
    o[7] = fmaxf(acc[7] * mul + b1.w, 0.f);
    if (nv && slot == 0) {
        uint4 w;
        w.x = pack2bf(o[0], o[1]);
        w.y = pack2bf(o[2], o[3]);
        w.z = pack2bf(o[4], o[5]);
        w.w = pack2bf(o[6], o[7]);
        out4[(size_t)n * 16 + f * 2 + c2] = w;   // node-major for dense consumers
    }
    if (MODE == 2) {
        float4 w0 = ((const float4*)Wp)[f * 4 + c2 * 2];
        float4 w1 = ((const float4*)Wp)[f * 4 + c2 * 2 + 1];
        float s = o[0] * w0.x + o[1] * w0.y + o[2] * w0.z + o[3] * w0.w +
                  o[4] * w1.x + o[5] * w1.y + o[6] * w1.z + o[7] * w1.w;
        s += __shfl_xor(s, 1, 64);               // combine c2 halves
        if (nv && (lane & 7) == 0) atomicAdd(&wgp[n], s);  // slice partial of h3.Wp
    }
}

__global__ __launch_bounds__(256) void k_agg1(const uint4* __restrict__ in4s,
                                              const int* __restrict__ in_cnt,
                                              const int* __restrict__ csr_pad,
                                              const float* __restrict__ nsv,
                                              const float* __restrict__ bias,
                                              uint4* __restrict__ out4, int N) {
    agg_body<0>(in4s, in_cnt, csr_pad, nsv, bias, out4, nullptr, nullptr, N);
}

__global__ __launch_bounds__(256) void k_agg(const uint4* __restrict__ in4s,
                                             const int* __restrict__ in_cnt,
                                             const int* __restrict__ csr_pad,
                                             const float* __restrict__ bias,
                                             uint4* __restrict__ out4, int N) {
    agg_body<1>(in4s, in_cnt, csr_pad, nullptr, bias, out4, nullptr, nullptr, N);
}

__global__ __launch_bounds__(256) void k_agg_gate(const uint4* __restrict__ in4s,
                                                  const int* __restrict__ in_cnt,
                                                  const int* __restrict__ csr_pad,
                                                  const float* __restrict__ bias,
                                                  uint4* __restrict__ out4,
                                                  const float* __restrict__ Wp,
                                                  float* __restrict__ wgp, int N) {
    agg_body<2>(in4s, in_cnt, csr_pad, nullptr, bias, out4, Wp, wgp, N);
}

// ---------------- MFMA GEMM: reads node-major hb, writes SLICE-MAJOR xwb -----------------------
__global__ __launch_bounds__(256) void k_xw_mfma(const unsigned* __restrict__ hb,
                                                 const int* __restrict__ out_cnt,
                                                 const unsigned* __restrict__ wTg,
                                                 unsigned* __restrict__ xwb, int N) {
    __shared__ unsigned wT[128 * 68];
    int t = threadIdx.x;
#pragma unroll
    for (int i = 0; i < 8; i++) {
        int idx = t + i * 256;
        int row = idx >> 4;
        int col = idx & 15;
        *(uint4*)&wT[row * 68 + col * 4] = ((const uint4*)wTg)[idx];
    }
    __syncthreads();
    int wave = t >> 6, lane = t & 63;
    int quad = lane >> 4, c = lane & 15;
    int m = blockIdx.x * 64 + wave * 16 + c;
    bool mv = m < N;
    f32x4 acc[8];
#pragma unroll
    for (int i = 0; i < 8; i++) acc[i] = (f32x4){0.f, 0.f, 0.f, 0.f};

#pragma unroll
    for (int ks = 0; ks < 4; ks++) {
        U16 av;
        if (mv) av.u = *(const uint4*)&hb[m * 64 + ks * 16 + quad * 4];
        else av.u = make_uint4(0, 0, 0, 0);
#pragma unroll
        for (int cb = 0; cb < 8; cb++) {
            U16 bv;
            bv.u = *(const uint4*)&wT[(cb * 16 + c) * 68 + ks * 16 + quad * 4];
            acc[cb] = __builtin_amdgcn_mfma_f32_16x16x32_bf16(av.b, bv.b, acc[cb], 0, 0, 0);
        }
    }
    int rowBase = blockIdx.x * 64 + wave * 16 + quad * 4;
#pragma unroll
    for (int r = 0; r < 4; r++) {
        int rowN = rowBase + r;
        float nrm = (rowN < N) ? rsqrtf((float)(out_cnt[rowN] + 1)) : 0.f;
#pragma unroll
        for (int cb = 0; cb < 8; cb++) {
            float v = acc[cb][r] * nrm;
            float vn = __shfl_xor(v, 1, 64);
            if (((c & 1) == 0) && rowN < N)
                xwb[(size_t)cb * N * 8 + (size_t)rowN * 8 + (c >> 1)] = pack2bf(v, vn);
        }
    }
}

// ---------------- pooling: weighted sum + max per graph (sigmoid applied here, R17) ------------
__device__ __forceinline__ int lower_bound(const int* a, int n, int key) {
    int lo = 0, hi = n;
    while (lo < hi) {
        int m = (lo + hi) >> 1;
        if (a[m] < key) lo = m + 1;
        else hi = m;
    }
    return lo;
}

__global__ __launch_bounds__(64) void k_pool(const unsigned* __restrict__ hb,
                                             const float* __restrict__ wgp,
                                             const float* __restrict__ bp,
                                             const int* __restrict__ gids,
                                             float* __restrict__ out, int N) {
    int g = blockIdx.x >> 4;
    int part = blockIdx.x & 15;
    int t = threadIdx.x;
    int start = lower_bound(gids, N, g);
    int end = lower_bound(gids, N, g + 1);
    float bp0 = bp[0];
    float2 sum = {0.f, 0.f}, mx = {0.f, 0.f};
    for (int n = start + part; n < end; n += 16) {
        float w = 0.f;
        if (t == 0) w = 1.f / (1.f + expf(-(wgp[n] + bp0)));
        w = __shfl(w, 0, 64);
        float2 v = unpack2bf(hb[n * 64 + t]);
        sum.x += v.x * w;
        sum.y += v.y * w;
        mx.x = fmaxf(mx.x, v.x);
        mx.y = fmaxf(mx.y, v.y);
    }
    atomicAdd(&out[g * 256 + 2 * t], sum.x);
    atomicAdd(&out[g * 256 + 2 * t + 1], sum.y);
    atomicMax((int*)&out[g * 256 + 128 + 2 * t], __float_as_int(mx.x));
    atomicMax((int*)&out[g * 256 + 128 + 2 * t + 1], __float_as_int(mx.y));
}

extern "C" void kernel_launch(void* const* d_in, const int* in_sizes, int n_in,
                              void* d_out, int out_size, void* d_ws, size_t ws_size,
                              hipStream_t stream) {
    const float* node_feats = (const float*)d_in[0];
    const int* src = (const int*)d_in[1];
    const int* dst = (const int*)d_in[2];
    const int* gids = (const int*)d_in[3];
    const float* W1 = (const float*)d_in[4];
    const float* b1 = (const float*)d_in[5];
    const float* W2 = (const float*)d_in[6];
    const float* b2 = (const float*)d_in[7];
    const float* W3 = (const float*)d_in[8];
    const float* b3 = (const float*)d_in[9];
    const float* Wp = (const float*)d_in[10];
    const float* bp = (const float*)d_in[11];
    float* out = (float*)d_out;

    const int N = in_sizes[3];
    const int E = in_sizes[1];
    const int G = out_size / 256;
    const int NB = (N + 2047) >> 11;   // buckets of 2048 nodes (<= NBMAX)

    // ---- workspace layout (bytes) ----
    char* ws = (char*)d_ws;
    size_t o = 0;
    int* cntD = (int*)(ws + o);          o += NBMAX * 4;   // zeroed
    int* cntS = (int*)(ws + o);          o += NBMAX * 4;   // zeroed
    int* in_cnt = (int*)(ws + o);        o += (size_t)N * 4;   // zeroed; atomically built by k_mega
    int* out_cnt = (int*)(ws + o);       o += (size_t)N * 4;   // zeroed; atomically built by k_mega
    float* wgp = (float*)(ws + o);       o += (size_t)N * 4;   // zeroed; gate pre-act (slice atomics)
    size_t zero_bytes = o;
    float* nsv = (float*)(ws + o);       o += (size_t)N * 4;   // rsqrt(out_deg+1), k_nrm (R14)
    o = (o + 15) & ~15ull;
    unsigned* wT1g = (unsigned*)(ws + o); o += 8192 * 4;
    unsigned* wT2g = (unsigned*)(ws + o); o += 8192 * 4;
    unsigned* wT3g = (unsigned*)(ws + o); o += 8192 * 4;
    unsigned* binD = (unsigned*)(ws + o); o += (size_t)NBMAX * BCAP * 4;
    unsigned short* binS = (unsigned short*)(ws + o); o += (size_t)NBMAX * BCAP * 2;
    o = (o + 15) & ~15ull;
    int* csr_pad = (int*)(ws + o);       o += (size_t)N * CAP * 4;
    unsigned* xwb = (unsigned*)(ws + o); o += (size_t)N * 64 * 4;  // slice-major [8][N][8]
    unsigned* hb = (unsigned*)(ws + o);  o += (size_t)N * 64 * 4;  // node-major [N][64]
    (void)ws_size;

    (void)hipMemsetAsync(d_ws, 0, zero_bytes, stream);
    (void)hipMemsetAsync(d_out, 0, (size_t)out_size * 4, stream);

    int binGrid = (E + 1023) / 1024;
    int mmGrid = (N + 63) / 64;
    int aggGrid = ((N + 31) / 32) * 8;   // 32 nodes/block x 8 feature-slices (R17)
    int nrmGrid = (N + 1023) / 1024;

    // Phase 1: bucket edges + W1/W2/W3 bf16-transpose prepack (3 tail blocks)
    k_bin<<<binGrid + 3, 256, 0, stream>>>(src, dst, E, binD, binS, cntD, cntS, NB, binGrid,
                                           W1, W2, W3, wT1g, wT2g, wT3g);
    // Phase 2: CSR-from-buckets (CSPLIT-way) + out-degree histogram + layer-1 MFMA GEMM
    k_mega<<<2 * NB * CSPLIT + mmGrid, 256, 0, stream>>>(binD, binS, cntD, cntS, in_cnt,
                                                         out_cnt, csr_pad, node_feats,
                                                         wT1g, xwb, N, NB);
    // nsv = rsqrt(out_deg+1) once
    k_nrm<<<nrmGrid, 256, 0, stream>>>(out_cnt, nsv, N);
    // layer-1 agg: xwb(slice-major) -> hb(node-major)
    k_agg1<<<aggGrid, 256, 0, stream>>>((const uint4*)xwb, in_cnt, csr_pad, nsv, b1,
                                        (uint4*)hb, N);
    // layer 2
    k_xw_mfma<<<mmGrid, 256, 0, stream>>>(hb, out_cnt, wT2g, xwb, N);
    k_agg<<<aggGrid, 256, 0, stream>>>((const uint4*)xwb, in_cnt, csr_pad, b2,
                                       (uint4*)hb, N);
    // layer 3 (+ gate partial dots -> wgp)
    k_xw_mfma<<<mmGrid, 256, 0, stream>>>(hb, out_cnt, wT3g, xwb, N);
    k_agg_gate<<<aggGrid, 256, 0, stream>>>((const uint4*)xwb, in_cnt, csr_pad, b3,
                                            (uint4*)hb, Wp, wgp, N);
    // pooling (applies sigmoid to wgp)
    k_pool<<<G * 16, 64, 0, stream>>>(hb, wgp, bp, gids, out, N);
}

// Round 7
// 477.035 us; speedup vs baseline: 1.2668x; 1.2668x over previous
//
#include <hip/hip_runtime.h>
#include <hip/hip_bf16.h>

#define DIM 128
#define CAP 64       // padded CSR row capacity; in-deg ~Poisson(16), P(>=64) astronomically small
#define NBMAX 64     // max buckets (node-space / 2048)
#define BCAP 36864   // per-bucket edge capacity; mean ~32.7k, +22 sigma margin
#define CSPLIT 8     // sub-blocks per bucket for CSR/hist build (straggler fix, R13)

typedef __attribute__((ext_vector_type(8))) short bf16x8;
typedef __attribute__((ext_vector_type(4))) float f32x4;
typedef __bf16 bf16x2 __attribute__((ext_vector_type(2)));
union U16 { uint4 u; bf16x8 b; };
union UB { unsigned u; bf16x2 h; };

// ---- bf16 pack/unpack helpers (manual, RNE) ----
__device__ __forceinline__ unsigned short f2bf(float f) {
    unsigned u = __float_as_uint(f);
    unsigned r = (u + 0x7fffu + ((u >> 16) & 1u)) >> 16;
    return (unsigned short)r;
}
__device__ __forceinline__ unsigned pack2bf(float a, float b) {
    return (unsigned)f2bf(a) | ((unsigned)f2bf(b) << 16);
}
__device__ __forceinline__ float2 unpack2bf(unsigned v) {
    float2 r;
    r.x = __uint_as_float(v << 16);
    r.y = __uint_as_float(v & 0xffff0000u);
    return r;
}
// R14: native-__bf16 extraction + fmaf -> eligible for gfx950 v_fma_mix_f32_bf16.
__device__ __forceinline__ void accum8m(float* acc, uint4 v, float s) {
    UB w0, w1, w2, w3;
    w0.u = v.x; w1.u = v.y; w2.u = v.z; w3.u = v.w;
    acc[0] = fmaf((float)w0.h[0], s, acc[0]);
    acc[1] = fmaf((float)w0.h[1], s, acc[1]);
    acc[2] = fmaf((float)w1.h[0], s, acc[2]);
    acc[3] = fmaf((float)w1.h[1], s, acc[3]);
    acc[4] = fmaf((float)w2.h[0], s, acc[4]);
    acc[5] = fmaf((float)w2.h[1], s, acc[5]);
    acc[6] = fmaf((float)w3.h[0], s, acc[6]);
    acc[7] = fmaf((float)w3.h[1], s, acc[7]);
}

// ================= k_bin: bucket edges (R12-verified) + W1/W2/W3 bf16-T prepack tail ============
__global__ __launch_bounds__(256) void k_bin(const int* __restrict__ src,
                                             const int* __restrict__ dst, int E,
                                             unsigned* __restrict__ binD,
                                             unsigned short* __restrict__ binS,
                                             int* __restrict__ cntD,
                                             int* __restrict__ cntS, int NB, int binGrid,
                                             const float* __restrict__ W1,
                                             const float* __restrict__ W2,
                                             const float* __restrict__ W3,
                                             unsigned* __restrict__ wT1g,
                                             unsigned* __restrict__ wT2g,
                                             unsigned* __restrict__ wT3g) {
    __shared__ int hD[NBMAX], hS[NBMAX], bD[NBMAX], bS[NBMAX];
    int t = threadIdx.x;
    if ((int)blockIdx.x >= binGrid) {
        // ---------- W^T bf16 prepack: wTg[n*64+kp] = pack(W[2kp][n], W[2kp+1][n]) ----------
        int w = blockIdx.x - binGrid;
        const float* Wsrc = (w == 0) ? W1 : (w == 1) ? W2 : W3;
        unsigned* wTg = (w == 0) ? wT1g : (w == 1) ? wT2g : wT3g;
        int n = t >> 1;
        int kp0 = (t & 1) * 32;
#pragma unroll
        for (int i = 0; i < 32; i++) {
            int kp = kp0 + i;
            wTg[n * 64 + kp] = pack2bf(Wsrc[(2 * kp) * DIM + n], Wsrc[(2 * kp + 1) * DIM + n]);
        }
        return;
    }
    if (t < NB) { hD[t] = 0; hS[t] = 0; }
    __syncthreads();
    int e0 = blockIdx.x * 1024 + t * 4;
    int s[4], d[4];
    bool v[4];
#pragma unroll
    for (int i = 0; i < 4; i++) {
        v[i] = (e0 + i) < E;
        s[i] = 0; d[i] = 0;
        if (v[i]) { s[i] = src[e0 + i]; d[i] = dst[e0 + i]; }
    }
#pragma unroll
    for (int i = 0; i < 4; i++) {
        if (v[i]) {
            atomicAdd(&hD[d[i] >> 11], 1);
            atomicAdd(&hS[s[i] >> 11], 1);
        }
    }
    __syncthreads();
    if (t < NB) {
        bD[t] = atomicAdd(&cntD[t], hD[t]);
        bS[t] = atomicAdd(&cntS[t], hS[t]);
        hD[t] = 0; hS[t] = 0;
    }
    __syncthreads();
#pragma unroll
    for (int i = 0; i < 4; i++) {
        if (v[i]) {
            int bd = d[i] >> 11;
            int r = atomicAdd(&hD[bd], 1);
            int idx = bD[bd] + r;
            if (idx < BCAP)
                binD[bd * BCAP + idx] = ((unsigned)(d[i] & 2047) << 17) | (unsigned)s[i];
            int bs = s[i] >> 11;
            int r2 = atomicAdd(&hS[bs], 1);
            int idx2 = bS[bs] + r2;
            if (idx2 < BCAP) binS[bs * BCAP + idx2] = (unsigned short)(s[i] & 2047);
        }
    }
}

// ===== k_mega: CSR-from-buckets + src-histogram + layer-1 MFMA GEMM (fp32 X -> bf16 frags) ======
// [0, NB*CSPLIT): CSR sub-blocks; [NB*CSPLIT, 2*NB*CSPLIT): out_cnt histogram; rest: GEMM1.
__global__ __launch_bounds__(256) void k_mega(const unsigned* __restrict__ binD,
                                              const unsigned short* __restrict__ binS,
                                              const int* __restrict__ cntD,
                                              const int* __restrict__ cntS,
                                              int* __restrict__ in_cnt,
                                              int* __restrict__ out_cnt,
                                              int* __restrict__ csr_pad,
                                              const float* __restrict__ x,
                                              const unsigned* __restrict__ wT1g,
                                              unsigned* __restrict__ xwb, int N,
                                              int NB) {
    __shared__ __align__(16) char smem[34816];  // union: wT 34 KB | counters 16 KB
    int bid = blockIdx.x;
    int t = threadIdx.x;

    if (bid < NB * CSPLIT) {
        // ---------- CSR build: sub-block `sub` of bucket `b` ----------
        int b = bid / CSPLIT;
        int sub = bid - b * CSPLIT;
        int* h = (int*)smem;             // 2048 local counters
        int* bArr = ((int*)smem) + 2048; // 2048 global base offsets
        for (int j = t; j < 2048; j += 256) h[j] = 0;
        __syncthreads();
        int base = b << 11;
        int nE = cntD[b];
        if (nE > BCAP) nE = BCAP;
        int chunk = (nE + CSPLIT - 1) / CSPLIT;
        int i0 = sub * chunk;
        int i1 = i0 + chunk;
        if (i1 > nE) i1 = nE;
        const unsigned* bb = &binD[b * BCAP];
        for (int i = i0 + t * 4; i < i1; i += 1024) {
            unsigned e[4];
            int k = i1 - i;
            if (k > 4) k = 4;
#pragma unroll
            for (int j = 0; j < 4; j++)
                if (j < k) e[j] = bb[i + j];
#pragma unroll
            for (int j = 0; j < 4; j++)
                if (j < k) atomicAdd(&h[e[j] >> 17], 1);
        }
        __syncthreads();
        for (int j = t; j < 2048; j += 256) {
            int hv = h[j];
            bArr[j] = hv ? atomicAdd(&in_cnt[base + j], hv) : 0;
            h[j] = 0;
        }
        __syncthreads();
        for (int i = i0 + t * 4; i < i1; i += 1024) {
            unsigned e[4];
            int k = i1 - i;
            if (k > 4) k = 4;
#pragma unroll
            for (int j = 0; j < 4; j++)
                if (j < k) e[j] = bb[i + j];
#pragma unroll
            for (int j = 0; j < 4; j++)
                if (j < k) {
                    int dl = (int)(e[j] >> 17);
                    int pos = bArr[dl] + atomicAdd(&h[dl], 1);
                    if (pos < CAP)
                        csr_pad[(size_t)(base + dl) * CAP + pos] = (int)(e[j] & 0x1FFFFu);
                }
        }
        return;
    }
    if (bid < 2 * NB * CSPLIT) {
        // ---------- out-degree histogram: sub-block of bucket ----------
        int bb2 = bid - NB * CSPLIT;
        int b = bb2 / CSPLIT;
        int sub = bb2 - b * CSPLIT;
        int* hist = (int*)smem;
        for (int j = t; j < 2048; j += 256) hist[j] = 0;
        __syncthreads();
        int base = b << 11;
        int nE = cntS[b];
        if (nE > BCAP) nE = BCAP;
        int chunk = (nE + CSPLIT - 1) / CSPLIT;
        int i0 = sub * chunk;
        int i1 = i0 + chunk;
        if (i1 > nE) i1 = nE;
        const unsigned short* bs = &binS[b * BCAP];
        for (int i = i0 + t * 4; i < i1; i += 1024) {
            unsigned short e[4];
            int k = i1 - i;
            if (k > 4) k = 4;
#pragma unroll
            for (int j = 0; j < 4; j++)
                if (j < k) e[j] = bs[i + j];
#pragma unroll
            for (int j = 0; j < 4; j++)
                if (j < k) atomicAdd(&hist[(int)e[j]], 1);
        }
        __syncthreads();
        for (int j = t; j < 2048; j += 256) {
            int hv = hist[j];
            if (hv) atomicAdd(&out_cnt[base + j], hv);
        }
        return;
    }
    // ---------- GEMM1 via MFMA: xwb = bf16(X @ W1) (unscaled) ----------
    int gb = bid - 2 * NB * CSPLIT;
    unsigned* wT = (unsigned*)smem;  // 128 rows x stride 68
#pragma unroll
    for (int i = 0; i < 8; i++) {
        int idx = t + i * 256;
        int row = idx >> 4;
        int col = idx & 15;
        *(uint4*)&wT[row * 68 + col * 4] = ((const uint4*)wT1g)[idx];
    }
    __syncthreads();
    int wave = t >> 6, lane = t & 63;
    int quad = lane >> 4, c = lane & 15;
    int m = gb * 64 + wave * 16 + c;
    bool mv = m < N;
    f32x4 acc[8];
#pragma unroll
    for (int i = 0; i < 8; i++) acc[i] = (f32x4){0.f, 0.f, 0.f, 0.f};

#pragma unroll
    for (int ks = 0; ks < 4; ks++) {
        U16 av;
        if (mv) {
            const float4* xr = (const float4*)&x[(size_t)m * DIM + ks * 32 + quad * 8];
            float4 f0 = xr[0], f1 = xr[1];
            av.u.x = pack2bf(f0.x, f0.y);
            av.u.y = pack2bf(f0.z, f0.w);
            av.u.z = pack2bf(f1.x, f1.y);
            av.u.w = pack2bf(f1.z, f1.w);
        } else {
            av.u = make_uint4(0, 0, 0, 0);
        }
#pragma unroll
        for (int cb = 0; cb < 8; cb++) {
            U16 bv;
            bv.u = *(const uint4*)&wT[(cb * 16 + c) * 68 + ks * 16 + quad * 4];
            acc[cb] = __builtin_amdgcn_mfma_f32_16x16x32_bf16(av.b, bv.b, acc[cb], 0, 0, 0);
        }
    }
    int rowBase = gb * 64 + wave * 16 + quad * 4;
#pragma unroll
    for (int r = 0; r < 4; r++) {
        int rowN = rowBase + r;
#pragma unroll
        for (int cb = 0; cb < 8; cb++) {
            float v = acc[cb][r];
            float vn = __shfl_xor(v, 1, 64);
            if (((c & 1) == 0) && rowN < N)
                xwb[rowN * 64 + cb * 8 + (c >> 1)] = pack2bf(v, vn);
        }
    }
}

// ---------------- CSR aggregation, R15 structure (reverted R16/R17); R18: inline rsqrt --------
// 4 nodes/wave, 16 lanes/node, deep-batch-16 gather (4x in-flight loads/wave).
// MODE 0: layer-1 (xwb unscaled; per-source rsqrt(out_cnt[s]+1) inline, final *ndv)
// MODE 1: layers 2/3 (xwb pre-scaled by nsrc; ndv folded into every FMA)
// MODE 2: MODE 1 + fused sigmoid gate
template <int MODE>
__device__ __forceinline__ void agg_body(const uint4* __restrict__ xwb4,
                                         const int* __restrict__ in_cnt,
                                         const int* __restrict__ csr_pad,
                                         const int* __restrict__ out_cnt,
                                         const float* __restrict__ bias,
                                         uint4* __restrict__ hb4,
                                         const float* __restrict__ Wp,
                                         const float* __restrict__ bp,
                                         float* __restrict__ wg, int N) {
    int wid = (blockIdx.x * 256 + threadIdx.x) >> 6;
    int lane = threadIdx.x & 63;
    int g = lane >> 4, c = lane & 15;
    int n = wid * 4 + g;
    bool nv = n < N;
    int deg_true = nv ? in_cnt[n] : 0;
    int deg = deg_true > CAP ? CAP : deg_true;
    float ndv = rsqrtf((float)(deg_true + 1));
    const int* row = csr_pad + (size_t)n * CAP;

    float acc[8];
#pragma unroll
    for (int i = 0; i < 8; i++) acc[i] = 0.f;

    if (nv) {
        float s0 = (MODE == 0) ? rsqrtf((float)(out_cnt[n] + 1)) : ndv;
        accum8m(acc, xwb4[(size_t)n * 16 + c], s0);  // self-loop
    }
    for (int p = 0; p < deg; p += 16) {
        // slab-load 16 indices (uniform addr within 16-lane group -> HW broadcast);
        // reading past deg inside the CAP-padded row is in-bounds (garbage never used).
        int4 r0 = *(const int4*)&row[p];
        int4 r1 = *(const int4*)&row[p + 4];
        int4 r2 = *(const int4*)&row[p + 8];
        int4 r3 = *(const int4*)&row[p + 12];
        int sidx[16];
        sidx[0] = r0.x;  sidx[1] = r0.y;  sidx[2] = r0.z;  sidx[3] = r0.w;
        sidx[4] = r1.x;  sidx[5] = r1.y;  sidx[6] = r1.z;  sidx[7] = r1.w;
        sidx[8] = r2.x;  sidx[9] = r2.y;  sidx[10] = r2.z; sidx[11] = r2.w;
        sidx[12] = r3.x; sidx[13] = r3.y; sidx[14] = r3.z; sidx[15] = r3.w;
        uint4 gv[16];
        float sc[16];
#pragma unroll
        for (int u = 0; u < 16; u++) {
            bool pv = (p + u) < deg;
            int s = pv ? sidx[u] : n;                 // invalid -> own row (cache-hot)
            gv[u] = xwb4[(size_t)s * 16 + c];
            if (MODE == 0)
                sc[u] = pv ? rsqrtf((float)(out_cnt[s] + 1)) : 0.f;
            else
                sc[u] = pv ? ndv : 0.f;
        }
#pragma unroll
        for (int u = 0; u < 16; u++) accum8m(acc, gv[u], sc[u]);
    }

    float mul = (MODE == 0) ? ndv : 1.f;
    float4 b0 = ((const float4*)bias)[2 * c];
    float4 b1 = ((const float4*)bias)[2 * c + 1];
    float o[8];
    o[0] = fmaxf(acc[0] * mul + b0.x, 0.f);
    o[1] = fmaxf(acc[1] * mul + b0.y, 0.f);
    o[2] = fmaxf(acc[2] * mul + b0.z, 0.f);
    o[3] = fmaxf(acc[3] * mul + b0.w, 0.f);
    o[4] = fmaxf(acc[4] * mul + b1.x, 0.f);
    o[5] = fmaxf(acc[5] * mul + b1.y, 0.f);
    o[6] = fmaxf(acc[6] * mul + b1.z, 0.f);
    o[7] = fmaxf(acc[7] * mul + b1.w, 0.f);
    if (nv) {
        uint4 w;
        w.x = pack2bf(o[0], o[1]);
        w.y = pack2bf(o[2], o[3]);
        w.z = pack2bf(o[4], o[5]);
        w.w = pack2bf(o[6], o[7]);
        hb4[(size_t)n * 16 + c] = w;
    }
    if (MODE == 2) {
        float4 w0 = ((const float4*)Wp)[2 * c];
        float4 w1 = ((const float4*)Wp)[2 * c + 1];
        float s = o[0] * w0.x + o[1] * w0.y + o[2] * w0.z + o[3] * w0.w +
                  o[4] * w1.x + o[5] * w1.y + o[6] * w1.z + o[7] * w1.w;
        s += __shfl_xor(s, 1, 64);
        s += __shfl_xor(s, 2, 64);
        s += __shfl_xor(s, 4, 64);
        s += __shfl_xor(s, 8, 64);
        if (nv && c == 0) wg[n] = 1.f / (1.f + expf(-(s + bp[0])));
    }
}

__global__ __launch_bounds__(256) void k_agg1(const uint4* __restrict__ xwb4,
                                              const int* __restrict__ in_cnt,
                                              const int* __restrict__ csr_pad,
                                              const int* __restrict__ out_cnt,
                                              const float* __restrict__ bias,
                                              uint4* __restrict__ hb4, int N) {
    agg_body<0>(xwb4, in_cnt, csr_pad, out_cnt, bias, hb4, nullptr, nullptr, nullptr, N);
}

__global__ __launch_bounds__(256) void k_agg(const uint4* __restrict__ xwb4,
                                             const int* __restrict__ in_cnt,
                                             const int* __restrict__ csr_pad,
                                             const float* __restrict__ bias,
                                             uint4* __restrict__ hb4, int N) {
    agg_body<1>(xwb4, in_cnt, csr_pad, nullptr, bias, hb4, nullptr, nullptr, nullptr, N);
}

__global__ __launch_bounds__(256) void k_agg_gate(const uint4* __restrict__ xwb4,
                                                  const int* __restrict__ in_cnt,
                                                  const int* __restrict__ csr_pad,
                                                  const float* __restrict__ bias,
                                                  uint4* __restrict__ hb4,
                                                  const float* __restrict__ Wp,
                                                  const float* __restrict__ bp,
                                                  float* __restrict__ wg, int N) {
    agg_body<2>(xwb4, in_cnt, csr_pad, nullptr, bias, hb4, Wp, bp, wg, N);
}

// ---------------- MFMA GEMM (packed-bf16 input, prepacked W^T): xwb = bf16(nsrc .* (H@W)) -------
__global__ __launch_bounds__(256) void k_xw_mfma(const unsigned* __restrict__ hb,
                                                 const int* __restrict__ out_cnt,
                                                 const unsigned* __restrict__ wTg,
                                                 unsigned* __restrict__ xwb, int N) {
    __shared__ unsigned wT[128 * 68];
    int t = threadIdx.x;
#pragma unroll
    for (int i = 0; i < 8; i++) {
        int idx = t + i * 256;
        int row = idx >> 4;
        int col = idx & 15;
        *(uint4*)&wT[row * 68 + col * 4] = ((const uint4*)wTg)[idx];
    }
    __syncthreads();
    int wave = t >> 6, lane = t & 63;
    int quad = lane >> 4, c = lane & 15;
    int m = blockIdx.x * 64 + wave * 16 + c;
    bool mv = m < N;
    f32x4 acc[8];
#pragma unroll
    for (int i = 0; i < 8; i++) acc[i] = (f32x4){0.f, 0.f, 0.f, 0.f};

#pragma unroll
    for (int ks = 0; ks < 4; ks++) {
        U16 av;
        if (mv) av.u = *(const uint4*)&hb[m * 64 + ks * 16 + quad * 4];
        else av.u = make_uint4(0, 0, 0, 0);
#pragma unroll
        for (int cb = 0; cb < 8; cb++) {
            U16 bv;
            bv.u = *(const uint4*)&wT[(cb * 16 + c) * 68 + ks * 16 + quad * 4];
            acc[cb] = __builtin_amdgcn_mfma_f32_16x16x32_bf16(av.b, bv.b, acc[cb], 0, 0, 0);
        }
    }
    int rowBase = blockIdx.x * 64 + wave * 16 + quad * 4;
#pragma unroll
    for (int r = 0; r < 4; r++) {
        int rowN = rowBase + r;
        float nrm = (rowN < N) ? rsqrtf((float)(out_cnt[rowN] + 1)) : 0.f;
#pragma unroll
        for (int cb = 0; cb < 8; cb++) {
            float v = acc[cb][r] * nrm;
            float vn = __shfl_xor(v, 1, 64);
            if (((c & 1) == 0) && rowN < N)
                xwb[rowN * 64 + cb * 8 + (c >> 1)] = pack2bf(v, vn);
        }
    }
}

// ---------------- pooling: weighted sum + max per graph ----------------
__device__ __forceinline__ int lower_bound(const int* a, int n, int key) {
    int lo = 0, hi = n;
    while (lo < hi) {
        int m = (lo + hi) >> 1;
        if (a[m] < key) lo = m + 1;
        else hi = m;
    }
    return lo;
}

__global__ __launch_bounds__(64) void k_pool(const unsigned* __restrict__ hb,
                                             const float* __restrict__ wg,
                                             const int* __restrict__ gids,
                                             float* __restrict__ out, int N) {
    int g = blockIdx.x >> 4;
    int part = blockIdx.x & 15;
    int t = threadIdx.x;
    int start = lower_bound(gids, N, g);
    int end = lower_bound(gids, N, g + 1);
    float2 sum = {0.f, 0.f}, mx = {0.f, 0.f};
    for (int n = start + part; n < end; n += 16) {
        float w = wg[n];
        float2 v = unpack2bf(hb[n * 64 + t]);
        sum.x += v.x * w;
        sum.y += v.y * w;
        mx.x = fmaxf(mx.x, v.x);
        mx.y = fmaxf(mx.y, v.y);
    }
    atomicAdd(&out[g * 256 + 2 * t], sum.x);
    atomicAdd(&out[g * 256 + 2 * t + 1], sum.y);
    atomicMax((int*)&out[g * 256 + 128 + 2 * t], __float_as_int(mx.x));
    atomicMax((int*)&out[g * 256 + 128 + 2 * t + 1], __float_as_int(mx.y));
}

extern "C" void kernel_launch(void* const* d_in, const int* in_sizes, int n_in,
                              void* d_out, int out_size, void* d_ws, size_t ws_size,
                              hipStream_t stream) {
    const float* node_feats = (const float*)d_in[0];
    const int* src = (const int*)d_in[1];
    const int* dst = (const int*)d_in[2];
    const int* gids = (const int*)d_in[3];
    const float* W1 = (const float*)d_in[4];
    const float* b1 = (const float*)d_in[5];
    const float* W2 = (const float*)d_in[6];
    const float* b2 = (const float*)d_in[7];
    const float* W3 = (const float*)d_in[8];
    const float* b3 = (const float*)d_in[9];
    const float* Wp = (const float*)d_in[10];
    const float* bp = (const float*)d_in[11];
    float* out = (float*)d_out;

    const int N = in_sizes[3];
    const int E = in_sizes[1];
    const int G = out_size / 256;
    const int NB = (N + 2047) >> 11;   // buckets of 2048 nodes (<= NBMAX)

    // ---- workspace layout (bytes) ----
    char* ws = (char*)d_ws;
    size_t o = 0;
    int* cntD = (int*)(ws + o);          o += NBMAX * 4;   // zeroed
    int* cntS = (int*)(ws + o);          o += NBMAX * 4;   // zeroed
    int* in_cnt = (int*)(ws + o);        o += (size_t)N * 4;   // zeroed; atomically built by k_mega
    int* out_cnt = (int*)(ws + o);       o += (size_t)N * 4;   // zeroed; atomically built by k_mega
    size_t zero_bytes = o;
    float* wg = (float*)(ws + o);        o += (size_t)N * 4;
    o = (o + 15) & ~15ull;
    unsigned* wT1g = (unsigned*)(ws + o); o += 8192 * 4;
    unsigned* wT2g = (unsigned*)(ws + o); o += 8192 * 4;
    unsigned* wT3g = (unsigned*)(ws + o); o += 8192 * 4;
    unsigned* binD = (unsigned*)(ws + o); o += (size_t)NBMAX * BCAP * 4;
    unsigned short* binS = (unsigned short*)(ws + o); o += (size_t)NBMAX * BCAP * 2;
    o = (o + 15) & ~15ull;
    int* csr_pad = (int*)(ws + o);       o += (size_t)N * CAP * 4;
    unsigned* xwb = (unsigned*)(ws + o); o += (size_t)N * 64 * 4;
    unsigned* hb = (unsigned*)(ws + o);  o += (size_t)N * 64 * 4;
    (void)ws_size;

    (void)hipMemsetAsync(d_ws, 0, zero_bytes, stream);
    (void)hipMemsetAsync(d_out, 0, (size_t)out_size * 4, stream);

    int binGrid = (E + 1023) / 1024;
    int mmGrid = (N + 63) / 64;
    int aggGrid = (N + 15) / 16;      // 4 nodes/wave, 4 waves/block

    // Phase 1: bucket edges + W1/W2/W3 bf16-transpose prepack (3 tail blocks)
    k_bin<<<binGrid + 3, 256, 0, stream>>>(src, dst, E, binD, binS, cntD, cntS, NB, binGrid,
                                           W1, W2, W3, wT1g, wT2g, wT3g);
    // Phase 2: CSR-from-buckets (CSPLIT-way) + out-degree histogram + layer-1 MFMA GEMM
    k_mega<<<2 * NB * CSPLIT + mmGrid, 256, 0, stream>>>(binD, binS, cntD, cntS, in_cnt,
                                                         out_cnt, csr_pad, node_feats,
                                                         wT1g, xwb, N, NB);
    // layer-1 aggregation (applies nsrc per source inline via rsqrt(out_cnt+1)): xwb -> h1 (hb)
    k_agg1<<<aggGrid, 256, 0, stream>>>((const uint4*)xwb, in_cnt, csr_pad, out_cnt, b1,
                                        (uint4*)hb, N);
    // layer 2
    k_xw_mfma<<<mmGrid, 256, 0, stream>>>(hb, out_cnt, wT2g, xwb, N);
    k_agg<<<aggGrid, 256, 0, stream>>>((const uint4*)xwb, in_cnt, csr_pad, b2,
                                       (uint4*)hb, N);
    // layer 3 (+ fused sigmoid gate)
    k_xw_mfma<<<mmGrid, 256, 0, stream>>>(hb, out_cnt, wT3g, xwb, N);
    k_agg_gate<<<aggGrid, 256, 0, stream>>>((const uint4*)xwb, in_cnt, csr_pad, b3,
                                            (uint4*)hb, Wp, bp, wg, N);
    // pooling
    k_pool<<<G * 16, 64, 0, stream>>>(hb, wg, gids, out, N);
}

// Round 8
// 445.827 us; speedup vs baseline: 1.3555x; 1.0700x over previous
//
#include <hip/hip_runtime.h>
#include <hip/hip_bf16.h>

#define DIM 128
#define CAP 64       // padded CSR row capacity; in-deg ~Poisson(16), P(>=64) astronomically small
#define NBMAX 64     // max buckets (node-space / 2048)
#define BCAP 36864   // per-bucket edge capacity; mean ~32.7k, +22 sigma margin
#define CSPLIT 8     // sub-blocks per bucket for CSR/hist build (straggler fix, R13)

typedef __attribute__((ext_vector_type(8))) short bf16x8;
typedef __attribute__((ext_vector_type(4))) float f32x4;
typedef __bf16 bf16x2 __attribute__((ext_vector_type(2)));
union U16 { uint4 u; bf16x8 b; };
union UB { unsigned u; bf16x2 h; };

// ---- bf16 pack/unpack helpers (manual, RNE) ----
__device__ __forceinline__ unsigned short f2bf(float f) {
    unsigned u = __float_as_uint(f);
    unsigned r = (u + 0x7fffu + ((u >> 16) & 1u)) >> 16;
    return (unsigned short)r;
}
__device__ __forceinline__ unsigned pack2bf(float a, float b) {
    return (unsigned)f2bf(a) | ((unsigned)f2bf(b) << 16);
}
__device__ __forceinline__ float2 unpack2bf(unsigned v) {
    float2 r;
    r.x = __uint_as_float(v << 16);
    r.y = __uint_as_float(v & 0xffff0000u);
    return r;
}
// R14: native-__bf16 extraction + fmaf -> eligible for gfx950 v_fma_mix_f32_bf16.
__device__ __forceinline__ void accum8m(float* acc, uint4 v, float s) {
    UB w0, w1, w2, w3;
    w0.u = v.x; w1.u = v.y; w2.u = v.z; w3.u = v.w;
    acc[0] = fmaf((float)w0.h[0], s, acc[0]);
    acc[1] = fmaf((float)w0.h[1], s, acc[1]);
    acc[2] = fmaf((float)w1.h[0], s, acc[2]);
    acc[3] = fmaf((float)w1.h[1], s, acc[3]);
    acc[4] = fmaf((float)w2.h[0], s, acc[4]);
    acc[5] = fmaf((float)w2.h[1], s, acc[5]);
    acc[6] = fmaf((float)w3.h[0], s, acc[6]);
    acc[7] = fmaf((float)w3.h[1], s, acc[7]);
}

// ================= k_bin: bucket edges (R12-verified) + W1/W2/W3 bf16-T prepack tail ============
__global__ __launch_bounds__(256) void k_bin(const int* __restrict__ src,
                                             const int* __restrict__ dst, int E,
                                             unsigned* __restrict__ binD,
                                             unsigned short* __restrict__ binS,
                                             int* __restrict__ cntD,
                                             int* __restrict__ cntS, int NB, int binGrid,
                                             const float* __restrict__ W1,
                                             const float* __restrict__ W2,
                                             const float* __restrict__ W3,
                                             unsigned* __restrict__ wT1g,
                                             unsigned* __restrict__ wT2g,
                                             unsigned* __restrict__ wT3g) {
    __shared__ int hD[NBMAX], hS[NBMAX], bD[NBMAX], bS[NBMAX];
    int t = threadIdx.x;
    if ((int)blockIdx.x >= binGrid) {
        // ---------- W^T bf16 prepack: wTg[n*64+kp] = pack(W[2kp][n], W[2kp+1][n]) ----------
        int w = blockIdx.x - binGrid;
        const float* Wsrc = (w == 0) ? W1 : (w == 1) ? W2 : W3;
        unsigned* wTg = (w == 0) ? wT1g : (w == 1) ? wT2g : wT3g;
        int n = t >> 1;
        int kp0 = (t & 1) * 32;
#pragma unroll
        for (int i = 0; i < 32; i++) {
            int kp = kp0 + i;
            wTg[n * 64 + kp] = pack2bf(Wsrc[(2 * kp) * DIM + n], Wsrc[(2 * kp + 1) * DIM + n]);
        }
        return;
    }
    if (t < NB) { hD[t] = 0; hS[t] = 0; }
    __syncthreads();
    int e0 = blockIdx.x * 1024 + t * 4;
    int s[4], d[4];
    bool v[4];
#pragma unroll
    for (int i = 0; i < 4; i++) {
        v[i] = (e0 + i) < E;
        s[i] = 0; d[i] = 0;
        if (v[i]) { s[i] = src[e0 + i]; d[i] = dst[e0 + i]; }
    }
#pragma unroll
    for (int i = 0; i < 4; i++) {
        if (v[i]) {
            atomicAdd(&hD[d[i] >> 11], 1);
            atomicAdd(&hS[s[i] >> 11], 1);
        }
    }
    __syncthreads();
    if (t < NB) {
        bD[t] = atomicAdd(&cntD[t], hD[t]);
        bS[t] = atomicAdd(&cntS[t], hS[t]);
        hD[t] = 0; hS[t] = 0;
    }
    __syncthreads();
#pragma unroll
    for (int i = 0; i < 4; i++) {
        if (v[i]) {
            int bd = d[i] >> 11;
            int r = atomicAdd(&hD[bd], 1);
            int idx = bD[bd] + r;
            if (idx < BCAP)
                binD[bd * BCAP + idx] = ((unsigned)(d[i] & 2047) << 17) | (unsigned)s[i];
            int bs = s[i] >> 11;
            int r2 = atomicAdd(&hS[bs], 1);
            int idx2 = bS[bs] + r2;
            if (idx2 < BCAP) binS[bs * BCAP + idx2] = (unsigned short)(s[i] & 2047);
        }
    }
}

// ===== k_mega: CSR-from-buckets + src-histogram + layer-1 MFMA GEMM (fp32 X -> bf16 frags) ======
// [0, NB*CSPLIT): CSR sub-blocks; [NB*CSPLIT, 2*NB*CSPLIT): out_cnt histogram; rest: GEMM1.
__global__ __launch_bounds__(256) void k_mega(const unsigned* __restrict__ binD,
                                              const unsigned short* __restrict__ binS,
                                              const int* __restrict__ cntD,
                                              const int* __restrict__ cntS,
                                              int* __restrict__ in_cnt,
                                              int* __restrict__ out_cnt,
                                              int* __restrict__ csr_pad,
                                              const float* __restrict__ x,
                                              const unsigned* __restrict__ wT1g,
                                              unsigned* __restrict__ xwb, int N,
                                              int NB) {
    __shared__ __align__(16) char smem[34816];  // union: wT 34 KB | counters 16 KB
    int bid = blockIdx.x;
    int t = threadIdx.x;

    if (bid < NB * CSPLIT) {
        // ---------- CSR build: sub-block `sub` of bucket `b` ----------
        int b = bid / CSPLIT;
        int sub = bid - b * CSPLIT;
        int* h = (int*)smem;             // 2048 local counters
        int* bArr = ((int*)smem) + 2048; // 2048 global base offsets
        for (int j = t; j < 2048; j += 256) h[j] = 0;
        __syncthreads();
        int base = b << 11;
        int nE = cntD[b];
        if (nE > BCAP) nE = BCAP;
        int chunk = (nE + CSPLIT - 1) / CSPLIT;
        int i0 = sub * chunk;
        int i1 = i0 + chunk;
        if (i1 > nE) i1 = nE;
        const unsigned* bb = &binD[b * BCAP];
        for (int i = i0 + t * 4; i < i1; i += 1024) {
            unsigned e[4];
            int k = i1 - i;
            if (k > 4) k = 4;
#pragma unroll
            for (int j = 0; j < 4; j++)
                if (j < k) e[j] = bb[i + j];
#pragma unroll
            for (int j = 0; j < 4; j++)
                if (j < k) atomicAdd(&h[e[j] >> 17], 1);
        }
        __syncthreads();
        for (int j = t; j < 2048; j += 256) {
            int hv = h[j];
            bArr[j] = hv ? atomicAdd(&in_cnt[base + j], hv) : 0;
            h[j] = 0;
        }
        __syncthreads();
        for (int i = i0 + t * 4; i < i1; i += 1024) {
            unsigned e[4];
            int k = i1 - i;
            if (k > 4) k = 4;
#pragma unroll
            for (int j = 0; j < 4; j++)
                if (j < k) e[j] = bb[i + j];
#pragma unroll
            for (int j = 0; j < 4; j++)
                if (j < k) {
                    int dl = (int)(e[j] >> 17);
                    int pos = bArr[dl] + atomicAdd(&h[dl], 1);
                    if (pos < CAP)
                        csr_pad[(size_t)(base + dl) * CAP + pos] = (int)(e[j] & 0x1FFFFu);
                }
        }
        return;
    }
    if (bid < 2 * NB * CSPLIT) {
        // ---------- out-degree histogram: sub-block of bucket ----------
        int bb2 = bid - NB * CSPLIT;
        int b = bb2 / CSPLIT;
        int sub = bb2 - b * CSPLIT;
        int* hist = (int*)smem;
        for (int j = t; j < 2048; j += 256) hist[j] = 0;
        __syncthreads();
        int base = b << 11;
        int nE = cntS[b];
        if (nE > BCAP) nE = BCAP;
        int chunk = (nE + CSPLIT - 1) / CSPLIT;
        int i0 = sub * chunk;
        int i1 = i0 + chunk;
        if (i1 > nE) i1 = nE;
        const unsigned short* bs = &binS[b * BCAP];
        for (int i = i0 + t * 4; i < i1; i += 1024) {
            unsigned short e[4];
            int k = i1 - i;
            if (k > 4) k = 4;
#pragma unroll
            for (int j = 0; j < 4; j++)
                if (j < k) e[j] = bs[i + j];
#pragma unroll
            for (int j = 0; j < 4; j++)
                if (j < k) atomicAdd(&hist[(int)e[j]], 1);
        }
        __syncthreads();
        for (int j = t; j < 2048; j += 256) {
            int hv = hist[j];
            if (hv) atomicAdd(&out_cnt[base + j], hv);
        }
        return;
    }
    // ---------- GEMM1 via MFMA: xwb = bf16(X @ W1) (unscaled) ----------
    int gb = bid - 2 * NB * CSPLIT;
    unsigned* wT = (unsigned*)smem;  // 128 rows x stride 68
#pragma unroll
    for (int i = 0; i < 8; i++) {
        int idx = t + i * 256;
        int row = idx >> 4;
        int col = idx & 15;
        *(uint4*)&wT[row * 68 + col * 4] = ((const uint4*)wT1g)[idx];
    }
    __syncthreads();
    int wave = t >> 6, lane = t & 63;
    int quad = lane >> 4, c = lane & 15;
    int m = gb * 64 + wave * 16 + c;
    bool mv = m < N;
    f32x4 acc[8];
#pragma unroll
    for (int i = 0; i < 8; i++) acc[i] = (f32x4){0.f, 0.f, 0.f, 0.f};

#pragma unroll
    for (int ks = 0; ks < 4; ks++) {
        U16 av;
        if (mv) {
            const float4* xr = (const float4*)&x[(size_t)m * DIM + ks * 32 + quad * 8];
            float4 f0 = xr[0], f1 = xr[1];
            av.u.x = pack2bf(f0.x, f0.y);
            av.u.y = pack2bf(f0.z, f0.w);
            av.u.z = pack2bf(f1.x, f1.y);
            av.u.w = pack2bf(f1.z, f1.w);
        } else {
            av.u = make_uint4(0, 0, 0, 0);
        }
#pragma unroll
        for (int cb = 0; cb < 8; cb++) {
            U16 bv;
            bv.u = *(const uint4*)&wT[(cb * 16 + c) * 68 + ks * 16 + quad * 4];
            acc[cb] = __builtin_amdgcn_mfma_f32_16x16x32_bf16(av.b, bv.b, acc[cb], 0, 0, 0);
        }
    }
    int rowBase = gb * 64 + wave * 16 + quad * 4;
#pragma unroll
    for (int r = 0; r < 4; r++) {
        int rowN = rowBase + r;
#pragma unroll
        for (int cb = 0; cb < 8; cb++) {
            float v = acc[cb][r];
            float vn = __shfl_xor(v, 1, 64);
            if (((c & 1) == 0) && rowN < N)
                xwb[rowN * 64 + cb * 8 + (c >> 1)] = pack2bf(v, vn);
        }
    }
}

// ---------------- k_nrm: precompute nsv[n] = rsqrt(out_deg+1) (R14; 400 KB, L2-resident) -------
// R18 lesson: inlining this rsqrt into the agg gather loop cost +30us (redundant quarter-rate
// transcendentals on the latency-critical path). The L2-hot table load is strictly better.
__global__ __launch_bounds__(256) void k_nrm(const int* __restrict__ out_cnt,
                                             float* __restrict__ nsv, int N) {
    int i = (blockIdx.x * 256 + threadIdx.x) * 4;
    if (i + 3 < N) {
        int4 d = *(const int4*)&out_cnt[i];
        float4 r;
        r.x = rsqrtf((float)(d.x + 1));
        r.y = rsqrtf((float)(d.y + 1));
        r.z = rsqrtf((float)(d.z + 1));
        r.w = rsqrtf((float)(d.w + 1));
        *(float4*)&nsv[i] = r;
    } else {
        for (int j = i; j < N && j < i + 4; j++) nsv[j] = rsqrtf((float)(out_cnt[j] + 1));
    }
}

// ---------------- CSR aggregation, R15 structure (best measured: 444.8us total) ----------------
// 4 nodes/wave, 16 lanes/node, deep-batch-16 gather (16 in-flight loads before consumption).
// Invalid slots redirect to the node's own row (cache-hot) with scale 0 -> uniform control flow.
// MODE 0: layer-1 (xwb unscaled; per-source scale nsv[s], final *ndv)
// MODE 1: layers 2/3 (xwb pre-scaled by nsrc; ndv folded into every FMA)
// MODE 2: MODE 1 + fused sigmoid gate
template <int MODE>
__device__ __forceinline__ void agg_body(const uint4* __restrict__ xwb4,
                                         const int* __restrict__ in_cnt,
                                         const int* __restrict__ csr_pad,
                                         const float* __restrict__ nsv,
                                         const float* __restrict__ bias,
                                         uint4* __restrict__ hb4,
                                         const float* __restrict__ Wp,
                                         const float* __restrict__ bp,
                                         float* __restrict__ wg, int N) {
    int wid = (blockIdx.x * 256 + threadIdx.x) >> 6;
    int lane = threadIdx.x & 63;
    int g = lane >> 4, c = lane & 15;
    int n = wid * 4 + g;
    bool nv = n < N;
    int deg_true = nv ? in_cnt[n] : 0;
    int deg = deg_true > CAP ? CAP : deg_true;
    float ndv = rsqrtf((float)(deg_true + 1));
    const int* row = csr_pad + (size_t)n * CAP;

    float acc[8];
#pragma unroll
    for (int i = 0; i < 8; i++) acc[i] = 0.f;

    if (nv) {
        float s0 = (MODE == 0) ? nsv[n] : ndv;
        accum8m(acc, xwb4[(size_t)n * 16 + c], s0);  // self-loop
    }
    for (int p = 0; p < deg; p += 16) {
        // slab-load 16 indices (uniform addr within 16-lane group -> HW broadcast);
        // reading past deg inside the CAP-padded row is in-bounds (garbage never used).
        int4 r0 = *(const int4*)&row[p];
        int4 r1 = *(const int4*)&row[p + 4];
        int4 r2 = *(const int4*)&row[p + 8];
        int4 r3 = *(const int4*)&row[p + 12];
        int sidx[16];
        sidx[0] = r0.x;  sidx[1] = r0.y;  sidx[2] = r0.z;  sidx[3] = r0.w;
        sidx[4] = r1.x;  sidx[5] = r1.y;  sidx[6] = r1.z;  sidx[7] = r1.w;
        sidx[8] = r2.x;  sidx[9] = r2.y;  sidx[10] = r2.z; sidx[11] = r2.w;
        sidx[12] = r3.x; sidx[13] = r3.y; sidx[14] = r3.z; sidx[15] = r3.w;
        uint4 gv[16];
        float sc[16];
#pragma unroll
        for (int u = 0; u < 16; u++) {
            bool pv = (p + u) < deg;
            int s = pv ? sidx[u] : n;                 // invalid -> own row (cache-hot)
            gv[u] = xwb4[(size_t)s * 16 + c];
            if (MODE == 0)
                sc[u] = pv ? nsv[s] : 0.f;
            else
                sc[u] = pv ? ndv : 0.f;
        }
#pragma unroll
        for (int u = 0; u < 16; u++) accum8m(acc, gv[u], sc[u]);
    }

    float mul = (MODE == 0) ? ndv : 1.f;
    float4 b0 = ((const float4*)bias)[2 * c];
    float4 b1 = ((const float4*)bias)[2 * c + 1];
    float o[8];
    o[0] = fmaxf(acc[0] * mul + b0.x, 0.f);
    o[1] = fmaxf(acc[1] * mul + b0.y, 0.f);
    o[2] = fmaxf(acc[2] * mul + b0.z, 0.f);
    o[3] = fmaxf(acc[3] * mul + b0.w, 0.f);
    o[4] = fmaxf(acc[4] * mul + b1.x, 0.f);
    o[5] = fmaxf(acc[5] * mul + b1.y, 0.f);
    o[6] = fmaxf(acc[6] * mul + b1.z, 0.f);
    o[7] = fmaxf(acc[7] * mul + b1.w, 0.f);
    if (nv) {
        uint4 w;
        w.x = pack2bf(o[0], o[1]);
        w.y = pack2bf(o[2], o[3]);
        w.z = pack2bf(o[4], o[5]);
        w.w = pack2bf(o[6], o[7]);
        hb4[(size_t)n * 16 + c] = w;
    }
    if (MODE == 2) {
        float4 w0 = ((const float4*)Wp)[2 * c];
        float4 w1 = ((const float4*)Wp)[2 * c + 1];
        float s = o[0] * w0.x + o[1] * w0.y + o[2] * w0.z + o[3] * w0.w +
                  o[4] * w1.x + o[5] * w1.y + o[6] * w1.z + o[7] * w1.w;
        s += __shfl_xor(s, 1, 64);
        s += __shfl_xor(s, 2, 64);
        s += __shfl_xor(s, 4, 64);
        s += __shfl_xor(s, 8, 64);
        if (nv && c == 0) wg[n] = 1.f / (1.f + expf(-(s + bp[0])));
    }
}

__global__ __launch_bounds__(256) void k_agg1(const uint4* __restrict__ xwb4,
                                              const int* __restrict__ in_cnt,
                                              const int* __restrict__ csr_pad,
                                              const float* __restrict__ nsv,
                                              const float* __restrict__ bias,
                                              uint4* __restrict__ hb4, int N) {
    agg_body<0>(xwb4, in_cnt, csr_pad, nsv, bias, hb4, nullptr, nullptr, nullptr, N);
}

__global__ __launch_bounds__(256) void k_agg(const uint4* __restrict__ xwb4,
                                             const int* __restrict__ in_cnt,
                                             const int* __restrict__ csr_pad,
                                             const float* __restrict__ bias,
                                             uint4* __restrict__ hb4, int N) {
    agg_body<1>(xwb4, in_cnt, csr_pad, nullptr, bias, hb4, nullptr, nullptr, nullptr, N);
}

__global__ __launch_bounds__(256) void k_agg_gate(const uint4* __restrict__ xwb4,
                                                  const int* __restrict__ in_cnt,
                                                  const int* __restrict__ csr_pad,
                                                  const float* __restrict__ bias,
                                                  uint4* __restrict__ hb4,
                                                  const float* __restrict__ Wp,
                                                  const float* __restrict__ bp,
                                                  float* __restrict__ wg, int N) {
    agg_body<2>(xwb4, in_cnt, csr_pad, nullptr, bias, hb4, Wp, bp, wg, N);
}

// ---------------- MFMA GEMM (packed-bf16 input, prepacked W^T): xwb = bf16(nsrc .* (H@W)) -------
__global__ __launch_bounds__(256) void k_xw_mfma(const unsigned* __restrict__ hb,
                                                 const int* __restrict__ out_cnt,
                                                 const unsigned* __restrict__ wTg,
                                                 unsigned* __restrict__ xwb, int N) {
    __shared__ unsigned wT[128 * 68];
    int t = threadIdx.x;
#pragma unroll
    for (int i = 0; i < 8; i++) {
        int idx = t + i * 256;
        int row = idx >> 4;
        int col = idx & 15;
        *(uint4*)&wT[row * 68 + col * 4] = ((const uint4*)wTg)[idx];
    }
    __syncthreads();
    int wave = t >> 6, lane = t & 63;
    int quad = lane >> 4, c = lane & 15;
    int m = blockIdx.x * 64 + wave * 16 + c;
    bool mv = m < N;
    f32x4 acc[8];
#pragma unroll
    for (int i = 0; i < 8; i++) acc[i] = (f32x4){0.f, 0.f, 0.f, 0.f};

#pragma unroll
    for (int ks = 0; ks < 4; ks++) {
        U16 av;
        if (mv) av.u = *(const uint4*)&hb[m * 64 + ks * 16 + quad * 4];
        else av.u = make_uint4(0, 0, 0, 0);
#pragma unroll
        for (int cb = 0; cb < 8; cb++) {
            U16 bv;
            bv.u = *(const uint4*)&wT[(cb * 16 + c) * 68 + ks * 16 + quad * 4];
            acc[cb] = __builtin_amdgcn_mfma_f32_16x16x32_bf16(av.b, bv.b, acc[cb], 0, 0, 0);
        }
    }
    int rowBase = blockIdx.x * 64 + wave * 16 + quad * 4;
#pragma unroll
    for (int r = 0; r < 4; r++) {
        int rowN = rowBase + r;
        float nrm = (rowN < N) ? rsqrtf((float)(out_cnt[rowN] + 1)) : 0.f;
#pragma unroll
        for (int cb = 0; cb < 8; cb++) {
            float v = acc[cb][r] * nrm;
            float vn = __shfl_xor(v, 1, 64);
            if (((c & 1) == 0) && rowN < N)
                xwb[rowN * 64 + cb * 8 + (c >> 1)] = pack2bf(v, vn);
        }
    }
}

// ---------------- pooling: weighted sum + max per graph ----------------
__device__ __forceinline__ int lower_bound(const int* a, int n, int key) {
    int lo = 0, hi = n;
    while (lo < hi) {
        int m = (lo + hi) >> 1;
        if (a[m] < key) lo = m + 1;
        else hi = m;
    }
    return lo;
}

__global__ __launch_bounds__(64) void k_pool(const unsigned* __restrict__ hb,
                                             const float* __restrict__ wg,
                                             const int* __restrict__ gids,
                                             float* __restrict__ out, int N) {
    int g = blockIdx.x >> 4;
    int part = blockIdx.x & 15;
    int t = threadIdx.x;
    int start = lower_bound(gids, N, g);
    int end = lower_bound(gids, N, g + 1);
    float2 sum = {0.f, 0.f}, mx = {0.f, 0.f};
    for (int n = start + part; n < end; n += 16) {
        float w = wg[n];
        float2 v = unpack2bf(hb[n * 64 + t]);
        sum.x += v.x * w;
        sum.y += v.y * w;
        mx.x = fmaxf(mx.x, v.x);
        mx.y = fmaxf(mx.y, v.y);
    }
    atomicAdd(&out[g * 256 + 2 * t], sum.x);
    atomicAdd(&out[g * 256 + 2 * t + 1], sum.y);
    atomicMax((int*)&out[g * 256 + 128 + 2 * t], __float_as_int(mx.x));
    atomicMax((int*)&out[g * 256 + 128 + 2 * t + 1], __float_as_int(mx.y));
}

extern "C" void kernel_launch(void* const* d_in, const int* in_sizes, int n_in,
                              void* d_out, int out_size, void* d_ws, size_t ws_size,
                              hipStream_t stream) {
    const float* node_feats = (const float*)d_in[0];
    const int* src = (const int*)d_in[1];
    const int* dst = (const int*)d_in[2];
    const int* gids = (const int*)d_in[3];
    const float* W1 = (const float*)d_in[4];
    const float* b1 = (const float*)d_in[5];
    const float* W2 = (const float*)d_in[6];
    const float* b2 = (const float*)d_in[7];
    const float* W3 = (const float*)d_in[8];
    const float* b3 = (const float*)d_in[9];
    const float* Wp = (const float*)d_in[10];
    const float* bp = (const float*)d_in[11];
    float* out = (float*)d_out;

    const int N = in_sizes[3];
    const int E = in_sizes[1];
    const int G = out_size / 256;
    const int NB = (N + 2047) >> 11;   // buckets of 2048 nodes (<= NBMAX)

    // ---- workspace layout (bytes) ----
    char* ws = (char*)d_ws;
    size_t o = 0;
    int* cntD = (int*)(ws + o);          o += NBMAX * 4;   // zeroed
    int* cntS = (int*)(ws + o);          o += NBMAX * 4;   // zeroed
    int* in_cnt = (int*)(ws + o);        o += (size_t)N * 4;   // zeroed; atomically built by k_mega
    int* out_cnt = (int*)(ws + o);       o += (size_t)N * 4;   // zeroed; atomically built by k_mega
    size_t zero_bytes = o;
    float* wg = (float*)(ws + o);        o += (size_t)N * 4;
    float* nsv = (float*)(ws + o);       o += (size_t)N * 4;   // rsqrt(out_deg+1), k_nrm (R14)
    o = (o + 15) & ~15ull;
    unsigned* wT1g = (unsigned*)(ws + o); o += 8192 * 4;
    unsigned* wT2g = (unsigned*)(ws + o); o += 8192 * 4;
    unsigned* wT3g = (unsigned*)(ws + o); o += 8192 * 4;
    unsigned* binD = (unsigned*)(ws + o); o += (size_t)NBMAX * BCAP * 4;
    unsigned short* binS = (unsigned short*)(ws + o); o += (size_t)NBMAX * BCAP * 2;
    o = (o + 15) & ~15ull;
    int* csr_pad = (int*)(ws + o);       o += (size_t)N * CAP * 4;
    unsigned* xwb = (unsigned*)(ws + o); o += (size_t)N * 64 * 4;
    unsigned* hb = (unsigned*)(ws + o);  o += (size_t)N * 64 * 4;
    (void)ws_size;

    (void)hipMemsetAsync(d_ws, 0, zero_bytes, stream);
    (void)hipMemsetAsync(d_out, 0, (size_t)out_size * 4, stream);

    int binGrid = (E + 1023) / 1024;
    int mmGrid = (N + 63) / 64;
    int aggGrid = (N + 15) / 16;      // 4 nodes/wave, 4 waves/block
    int nrmGrid = (N + 1023) / 1024;

    // Phase 1: bucket edges + W1/W2/W3 bf16-transpose prepack (3 tail blocks)
    k_bin<<<binGrid + 3, 256, 0, stream>>>(src, dst, E, binD, binS, cntD, cntS, NB, binGrid,
                                           W1, W2, W3, wT1g, wT2g, wT3g);
    // Phase 2: CSR-from-buckets (CSPLIT-way) + out-degree histogram + layer-1 MFMA GEMM
    k_mega<<<2 * NB * CSPLIT + mmGrid, 256, 0, stream>>>(binD, binS, cntD, cntS, in_cnt,
                                                         out_cnt, csr_pad, node_feats,
                                                         wT1g, xwb, N, NB);
    // nsv = rsqrt(out_deg+1) once (L2-hot table; do NOT inline into agg1 — R18 regression)
    k_nrm<<<nrmGrid, 256, 0, stream>>>(out_cnt, nsv, N);
    // layer-1 aggregation (applies nsrc per source inline): xwb -> h1 (hb)
    k_agg1<<<aggGrid, 256, 0, stream>>>((const uint4*)xwb, in_cnt, csr_pad, nsv, b1,
                                        (uint4*)hb, N);
    // layer 2
    k_xw_mfma<<<mmGrid, 256, 0, stream>>>(hb, out_cnt, wT2g, xwb, N);
    k_agg<<<aggGrid, 256, 0, stream>>>((const uint4*)xwb, in_cnt, csr_pad, b2,
                                       (uint4*)hb, N);
    // layer 3 (+ fused sigmoid gate)
    k_xw_mfma<<<mmGrid, 256, 0, stream>>>(hb, out_cnt, wT3g, xwb, N);
    k_agg_gate<<<aggGrid, 256, 0, stream>>>((const uint4*)xwb, in_cnt, csr_pad, b3,
                                            (uint4*)hb, Wp, bp, wg, N);
    // pooling
    k_pool<<<G * 16, 64, 0, stream>>>(hb, wg, gids, out, N);
}

// Round 9
// 445.804 us; speedup vs baseline: 1.3556x; 1.0001x over previous
//
#include <hip/hip_runtime.h>
#include <hip/hip_bf16.h>

#define DIM 128
#define CAP 64       // padded CSR row capacity; in-deg ~Poisson(16), P(>=64) astronomically small
#define NBMAX 64     // max buckets (node-space / 2048)
#define BCAP 36864   // per-bucket edge capacity; mean ~32.7k, +22 sigma margin
#define CSPLIT 8     // sub-blocks per bucket for CSR/hist build (straggler fix, R13)

typedef __attribute__((ext_vector_type(8))) short bf16x8;
typedef __attribute__((ext_vector_type(4))) float f32x4;
typedef __bf16 bf16x2 __attribute__((ext_vector_type(2)));
union U16 { uint4 u; bf16x8 b; };
union UB { unsigned u; bf16x2 h; };

// ---- bf16 pack/unpack helpers (manual, RNE) ----
__device__ __forceinline__ unsigned short f2bf(float f) {
    unsigned u = __float_as_uint(f);
    unsigned r = (u + 0x7fffu + ((u >> 16) & 1u)) >> 16;
    return (unsigned short)r;
}
__device__ __forceinline__ unsigned pack2bf(float a, float b) {
    return (unsigned)f2bf(a) | ((unsigned)f2bf(b) << 16);
}
__device__ __forceinline__ float2 unpack2bf(unsigned v) {
    float2 r;
    r.x = __uint_as_float(v << 16);
    r.y = __uint_as_float(v & 0xffff0000u);
    return r;
}
// R14: native-__bf16 extraction + fmaf -> eligible for gfx950 v_fma_mix_f32_bf16.
__device__ __forceinline__ void accum8m(float* acc, uint4 v, float s) {
    UB w0, w1, w2, w3;
    w0.u = v.x; w1.u = v.y; w2.u = v.z; w3.u = v.w;
    acc[0] = fmaf((float)w0.h[0], s, acc[0]);
    acc[1] = fmaf((float)w0.h[1], s, acc[1]);
    acc[2] = fmaf((float)w1.h[0], s, acc[2]);
    acc[3] = fmaf((float)w1.h[1], s, acc[3]);
    acc[4] = fmaf((float)w2.h[0], s, acc[4]);
    acc[5] = fmaf((float)w2.h[1], s, acc[5]);
    acc[6] = fmaf((float)w3.h[0], s, acc[6]);
    acc[7] = fmaf((float)w3.h[1], s, acc[7]);
}

// ================= k_bin: bucket edges + W prepack tail; R20: 4-way replicated LDS counters ====
// R20: NB=49 counters for 256 threads was ~5-way same-address pressure on LDS atomics across
// 4 passes x 1.6M edges. Replicate each bucket counter 4x (replica = tid&3); per-replica base
// offsets derived in the existing one-global-atomic-per-bucket merge. CSR is order-agnostic.
__global__ __launch_bounds__(256) void k_bin(const int* __restrict__ src,
                                             const int* __restrict__ dst, int E,
                                             unsigned* __restrict__ binD,
                                             unsigned short* __restrict__ binS,
                                             int* __restrict__ cntD,
                                             int* __restrict__ cntS, int NB, int binGrid,
                                             const float* __restrict__ W1,
                                             const float* __restrict__ W2,
                                             const float* __restrict__ W3,
                                             unsigned* __restrict__ wT1g,
                                             unsigned* __restrict__ wT2g,
                                             unsigned* __restrict__ wT3g) {
    __shared__ int hD[NBMAX * 4], hS[NBMAX * 4], bD[NBMAX * 4], bS[NBMAX * 4];
    int t = threadIdx.x;
    if ((int)blockIdx.x >= binGrid) {
        // ---------- W^T bf16 prepack: wTg[n*64+kp] = pack(W[2kp][n], W[2kp+1][n]) ----------
        int w = blockIdx.x - binGrid;
        const float* Wsrc = (w == 0) ? W1 : (w == 1) ? W2 : W3;
        unsigned* wTg = (w == 0) ? wT1g : (w == 1) ? wT2g : wT3g;
        int n = t >> 1;
        int kp0 = (t & 1) * 32;
#pragma unroll
        for (int i = 0; i < 32; i++) {
            int kp = kp0 + i;
            wTg[n * 64 + kp] = pack2bf(Wsrc[(2 * kp) * DIM + n], Wsrc[(2 * kp + 1) * DIM + n]);
        }
        return;
    }
    if (t < NB * 4) { hD[t] = 0; hS[t] = 0; }
    __syncthreads();
    int rep = t & 3;
    int e0 = blockIdx.x * 1024 + t * 4;
    int s[4], d[4];
    bool v[4];
#pragma unroll
    for (int i = 0; i < 4; i++) {
        v[i] = (e0 + i) < E;
        s[i] = 0; d[i] = 0;
        if (v[i]) { s[i] = src[e0 + i]; d[i] = dst[e0 + i]; }
    }
#pragma unroll
    for (int i = 0; i < 4; i++) {
        if (v[i]) {
            atomicAdd(&hD[(d[i] >> 11) * 4 + rep], 1);
            atomicAdd(&hS[(s[i] >> 11) * 4 + rep], 1);
        }
    }
    __syncthreads();
    if (t < NB) {
        int h0 = hD[t * 4], h1 = hD[t * 4 + 1], h2 = hD[t * 4 + 2], h3 = hD[t * 4 + 3];
        int base = atomicAdd(&cntD[t], h0 + h1 + h2 + h3);
        bD[t * 4] = base;
        bD[t * 4 + 1] = base + h0;
        bD[t * 4 + 2] = base + h0 + h1;
        bD[t * 4 + 3] = base + h0 + h1 + h2;
        hD[t * 4] = 0; hD[t * 4 + 1] = 0; hD[t * 4 + 2] = 0; hD[t * 4 + 3] = 0;
        int g0 = hS[t * 4], g1 = hS[t * 4 + 1], g2 = hS[t * 4 + 2], g3 = hS[t * 4 + 3];
        int bs = atomicAdd(&cntS[t], g0 + g1 + g2 + g3);
        bS[t * 4] = bs;
        bS[t * 4 + 1] = bs + g0;
        bS[t * 4 + 2] = bs + g0 + g1;
        bS[t * 4 + 3] = bs + g0 + g1 + g2;
        hS[t * 4] = 0; hS[t * 4 + 1] = 0; hS[t * 4 + 2] = 0; hS[t * 4 + 3] = 0;
    }
    __syncthreads();
#pragma unroll
    for (int i = 0; i < 4; i++) {
        if (v[i]) {
            int bd = (d[i] >> 11) * 4 + rep;
            int r = atomicAdd(&hD[bd], 1);
            int idx = bD[bd] + r;
            if (idx < BCAP)
                binD[(d[i] >> 11) * BCAP + idx] = ((unsigned)(d[i] & 2047) << 17) | (unsigned)s[i];
            int bs2 = (s[i] >> 11) * 4 + rep;
            int r2 = atomicAdd(&hS[bs2], 1);
            int idx2 = bS[bs2] + r2;
            if (idx2 < BCAP) binS[(s[i] >> 11) * BCAP + idx2] = (unsigned short)(s[i] & 2047);
        }
    }
}

// ===== k_mega: CSR-from-buckets + src-histogram + layer-1 MFMA GEMM (fp32 X -> bf16 frags) ======
// [0, NB*CSPLIT): CSR sub-blocks; [NB*CSPLIT, 2*NB*CSPLIT): out_cnt histogram; rest: GEMM1.
__global__ __launch_bounds__(256) void k_mega(const unsigned* __restrict__ binD,
                                              const unsigned short* __restrict__ binS,
                                              const int* __restrict__ cntD,
                                              const int* __restrict__ cntS,
                                              int* __restrict__ in_cnt,
                                              int* __restrict__ out_cnt,
                                              int* __restrict__ csr_pad,
                                              const float* __restrict__ x,
                                              const unsigned* __restrict__ wT1g,
                                              unsigned* __restrict__ xwb, int N,
                                              int NB) {
    __shared__ __align__(16) char smem[34816];  // union: wT 34 KB | counters 16 KB
    int bid = blockIdx.x;
    int t = threadIdx.x;

    if (bid < NB * CSPLIT) {
        // ---------- CSR build: sub-block `sub` of bucket `b` ----------
        int b = bid / CSPLIT;
        int sub = bid - b * CSPLIT;
        int* h = (int*)smem;             // 2048 local counters
        int* bArr = ((int*)smem) + 2048; // 2048 global base offsets
        for (int j = t; j < 2048; j += 256) h[j] = 0;
        __syncthreads();
        int base = b << 11;
        int nE = cntD[b];
        if (nE > BCAP) nE = BCAP;
        int chunk = (nE + CSPLIT - 1) / CSPLIT;
        int i0 = sub * chunk;
        int i1 = i0 + chunk;
        if (i1 > nE) i1 = nE;
        const unsigned* bb = &binD[b * BCAP];
        for (int i = i0 + t * 4; i < i1; i += 1024) {
            unsigned e[4];
            int k = i1 - i;
            if (k > 4) k = 4;
#pragma unroll
            for (int j = 0; j < 4; j++)
                if (j < k) e[j] = bb[i + j];
#pragma unroll
            for (int j = 0; j < 4; j++)
                if (j < k) atomicAdd(&h[e[j] >> 17], 1);
        }
        __syncthreads();
        for (int j = t; j < 2048; j += 256) {
            int hv = h[j];
            bArr[j] = hv ? atomicAdd(&in_cnt[base + j], hv) : 0;
            h[j] = 0;
        }
        __syncthreads();
        for (int i = i0 + t * 4; i < i1; i += 1024) {
            unsigned e[4];
            int k = i1 - i;
            if (k > 4) k = 4;
#pragma unroll
            for (int j = 0; j < 4; j++)
                if (j < k) e[j] = bb[i + j];
#pragma unroll
            for (int j = 0; j < 4; j++)
                if (j < k) {
                    int dl = (int)(e[j] >> 17);
                    int pos = bArr[dl] + atomicAdd(&h[dl], 1);
                    if (pos < CAP)
                        csr_pad[(size_t)(base + dl) * CAP + pos] = (int)(e[j] & 0x1FFFFu);
                }
        }
        return;
    }
    if (bid < 2 * NB * CSPLIT) {
        // ---------- out-degree histogram: sub-block of bucket ----------
        int bb2 = bid - NB * CSPLIT;
        int b = bb2 / CSPLIT;
        int sub = bb2 - b * CSPLIT;
        int* hist = (int*)smem;
        for (int j = t; j < 2048; j += 256) hist[j] = 0;
        __syncthreads();
        int base = b << 11;
        int nE = cntS[b];
        if (nE > BCAP) nE = BCAP;
        int chunk = (nE + CSPLIT - 1) / CSPLIT;
        int i0 = sub * chunk;
        int i1 = i0 + chunk;
        if (i1 > nE) i1 = nE;
        const unsigned short* bs = &binS[b * BCAP];
        for (int i = i0 + t * 4; i < i1; i += 1024) {
            unsigned short e[4];
            int k = i1 - i;
            if (k > 4) k = 4;
#pragma unroll
            for (int j = 0; j < 4; j++)
                if (j < k) e[j] = bs[i + j];
#pragma unroll
            for (int j = 0; j < 4; j++)
                if (j < k) atomicAdd(&hist[(int)e[j]], 1);
        }
        __syncthreads();
        for (int j = t; j < 2048; j += 256) {
            int hv = hist[j];
            if (hv) atomicAdd(&out_cnt[base + j], hv);
        }
        return;
    }
    // ---------- GEMM1 via MFMA: xwb = bf16(X @ W1) (unscaled) ----------
    int gb = bid - 2 * NB * CSPLIT;
    unsigned* wT = (unsigned*)smem;  // 128 rows x stride 68
#pragma unroll
    for (int i = 0; i < 8; i++) {
        int idx = t + i * 256;
        int row = idx >> 4;
        int col = idx & 15;
        *(uint4*)&wT[row * 68 + col * 4] = ((const uint4*)wT1g)[idx];
    }
    __syncthreads();
    int wave = t >> 6, lane = t & 63;
    int quad = lane >> 4, c = lane & 15;
    int m = gb * 64 + wave * 16 + c;
    bool mv = m < N;
    f32x4 acc[8];
#pragma unroll
    for (int i = 0; i < 8; i++) acc[i] = (f32x4){0.f, 0.f, 0.f, 0.f};

#pragma unroll
    for (int ks = 0; ks < 4; ks++) {
        U16 av;
        if (mv) {
            const float4* xr = (const float4*)&x[(size_t)m * DIM + ks * 32 + quad * 8];
            float4 f0 = xr[0], f1 = xr[1];
            av.u.x = pack2bf(f0.x, f0.y);
            av.u.y = pack2bf(f0.z, f0.w);
            av.u.z = pack2bf(f1.x, f1.y);
            av.u.w = pack2bf(f1.z, f1.w);
        } else {
            av.u = make_uint4(0, 0, 0, 0);
        }
#pragma unroll
        for (int cb = 0; cb < 8; cb++) {
            U16 bv;
            bv.u = *(const uint4*)&wT[(cb * 16 + c) * 68 + ks * 16 + quad * 4];
            acc[cb] = __builtin_amdgcn_mfma_f32_16x16x32_bf16(av.b, bv.b, acc[cb], 0, 0, 0);
        }
    }
    int rowBase = gb * 64 + wave * 16 + quad * 4;
#pragma unroll
    for (int r = 0; r < 4; r++) {
        int rowN = rowBase + r;
#pragma unroll
        for (int cb = 0; cb < 8; cb++) {
            float v = acc[cb][r];
            float vn = __shfl_xor(v, 1, 64);
            if (((c & 1) == 0) && rowN < N)
                xwb[rowN * 64 + cb * 8 + (c >> 1)] = pack2bf(v, vn);
        }
    }
}

// ---------------- k_nrm: precompute nsv[n] = rsqrt(out_deg+1) (R14; 400 KB, L2-resident) -------
// R18 lesson: inlining this rsqrt into the agg gather loop cost +30us (redundant quarter-rate
// transcendentals on the latency-critical path). The L2-hot table load is strictly better.
__global__ __launch_bounds__(256) void k_nrm(const int* __restrict__ out_cnt,
                                             float* __restrict__ nsv, int N) {
    int i = (blockIdx.x * 256 + threadIdx.x) * 4;
    if (i + 3 < N) {
        int4 d = *(const int4*)&out_cnt[i];
        float4 r;
        r.x = rsqrtf((float)(d.x + 1));
        r.y = rsqrtf((float)(d.y + 1));
        r.z = rsqrtf((float)(d.z + 1));
        r.w = rsqrtf((float)(d.w + 1));
        *(float4*)&nsv[i] = r;
    } else {
        for (int j = i; j < N && j < i + 4; j++) nsv[j] = rsqrtf((float)(out_cnt[j] + 1));
    }
}

// ---------------- CSR aggregation, R15 structure (best measured: 444.8us total) ----------------
// 4 nodes/wave, 16 lanes/node, deep-batch-16 gather (16 in-flight loads before consumption).
// Invalid slots redirect to the node's own row (cache-hot) with scale 0 -> uniform control flow.
// MODE 0: layer-1 (xwb unscaled; per-source scale nsv[s], final *ndv)
// MODE 1: layers 2/3 (xwb pre-scaled by nsrc; ndv folded into every FMA)
// MODE 2: MODE 1 + fused sigmoid gate
template <int MODE>
__device__ __forceinline__ void agg_body(const uint4* __restrict__ xwb4,
                                         const int* __restrict__ in_cnt,
                                         const int* __restrict__ csr_pad,
                                         const float* __restrict__ nsv,
                                         const float* __restrict__ bias,
                                         uint4* __restrict__ hb4,
                                         const float* __restrict__ Wp,
                                         const float* __restrict__ bp,
                                         float* __restrict__ wg, int N) {
    int wid = (blockIdx.x * 256 + threadIdx.x) >> 6;
    int lane = threadIdx.x & 63;
    int g = lane >> 4, c = lane & 15;
    int n = wid * 4 + g;
    bool nv = n < N;
    int deg_true = nv ? in_cnt[n] : 0;
    int deg = deg_true > CAP ? CAP : deg_true;
    float ndv = rsqrtf((float)(deg_true + 1));
    const int* row = csr_pad + (size_t)n * CAP;

    float acc[8];
#pragma unroll
    for (int i = 0; i < 8; i++) acc[i] = 0.f;

    if (nv) {
        float s0 = (MODE == 0) ? nsv[n] : ndv;
        accum8m(acc, xwb4[(size_t)n * 16 + c], s0);  // self-loop
    }
    for (int p = 0; p < deg; p += 16) {
        // slab-load 16 indices (uniform addr within 16-lane group -> HW broadcast);
        // reading past deg inside the CAP-padded row is in-bounds (garbage never used).
        int4 r0 = *(const int4*)&row[p];
        int4 r1 = *(const int4*)&row[p + 4];
        int4 r2 = *(const int4*)&row[p + 8];
        int4 r3 = *(const int4*)&row[p + 12];
        int sidx[16];
        sidx[0] = r0.x;  sidx[1] = r0.y;  sidx[2] = r0.z;  sidx[3] = r0.w;
        sidx[4] = r1.x;  sidx[5] = r1.y;  sidx[6] = r1.z;  sidx[7] = r1.w;
        sidx[8] = r2.x;  sidx[9] = r2.y;  sidx[10] = r2.z; sidx[11] = r2.w;
        sidx[12] = r3.x; sidx[13] = r3.y; sidx[14] = r3.z; sidx[15] = r3.w;
        uint4 gv[16];
        float sc[16];
#pragma unroll
        for (int u = 0; u < 16; u++) {
            bool pv = (p + u) < deg;
            int s = pv ? sidx[u] : n;                 // invalid -> own row (cache-hot)
            gv[u] = xwb4[(size_t)s * 16 + c];
            if (MODE == 0)
                sc[u] = pv ? nsv[s] : 0.f;
            else
                sc[u] = pv ? ndv : 0.f;
        }
#pragma unroll
        for (int u = 0; u < 16; u++) accum8m(acc, gv[u], sc[u]);
    }

    float mul = (MODE == 0) ? ndv : 1.f;
    float4 b0 = ((const float4*)bias)[2 * c];
    float4 b1 = ((const float4*)bias)[2 * c + 1];
    float o[8];
    o[0] = fmaxf(acc[0] * mul + b0.x, 0.f);
    o[1] = fmaxf(acc[1] * mul + b0.y, 0.f);
    o[2] = fmaxf(acc[2] * mul + b0.z, 0.f);
    o[3] = fmaxf(acc[3] * mul + b0.w, 0.f);
    o[4] = fmaxf(acc[4] * mul + b1.x, 0.f);
    o[5] = fmaxf(acc[5] * mul + b1.y, 0.f);
    o[6] = fmaxf(acc[6] * mul + b1.z, 0.f);
    o[7] = fmaxf(acc[7] * mul + b1.w, 0.f);
    if (nv) {
        uint4 w;
        w.x = pack2bf(o[0], o[1]);
        w.y = pack2bf(o[2], o[3]);
        w.z = pack2bf(o[4], o[5]);
        w.w = pack2bf(o[6], o[7]);
        hb4[(size_t)n * 16 + c] = w;
    }
    if (MODE == 2) {
        float4 w0 = ((const float4*)Wp)[2 * c];
        float4 w1 = ((const float4*)Wp)[2 * c + 1];
        float s = o[0] * w0.x + o[1] * w0.y + o[2] * w0.z + o[3] * w0.w +
                  o[4] * w1.x + o[5] * w1.y + o[6] * w1.z + o[7] * w1.w;
        s += __shfl_xor(s, 1, 64);
        s += __shfl_xor(s, 2, 64);
        s += __shfl_xor(s, 4, 64);
        s += __shfl_xor(s, 8, 64);
        if (nv && c == 0) wg[n] = 1.f / (1.f + expf(-(s + bp[0])));
    }
}

__global__ __launch_bounds__(256) void k_agg1(const uint4* __restrict__ xwb4,
                                              const int* __restrict__ in_cnt,
                                              const int* __restrict__ csr_pad,
                                              const float* __restrict__ nsv,
                                              const float* __restrict__ bias,
                                              uint4* __restrict__ hb4, int N) {
    agg_body<0>(xwb4, in_cnt, csr_pad, nsv, bias, hb4, nullptr, nullptr, nullptr, N);
}

__global__ __launch_bounds__(256) void k_agg(const uint4* __restrict__ xwb4,
                                             const int* __restrict__ in_cnt,
                                             const int* __restrict__ csr_pad,
                                             const float* __restrict__ bias,
                                             uint4* __restrict__ hb4, int N) {
    agg_body<1>(xwb4, in_cnt, csr_pad, nullptr, bias, hb4, nullptr, nullptr, nullptr, N);
}

__global__ __launch_bounds__(256) void k_agg_gate(const uint4* __restrict__ xwb4,
                                                  const int* __restrict__ in_cnt,
                                                  const int* __restrict__ csr_pad,
                                                  const float* __restrict__ bias,
                                                  uint4* __restrict__ hb4,
                                                  const float* __restrict__ Wp,
                                                  const float* __restrict__ bp,
                                                  float* __restrict__ wg, int N) {
    agg_body<2>(xwb4, in_cnt, csr_pad, nullptr, bias, hb4, Wp, bp, wg, N);
}

// ---------------- MFMA GEMM (packed-bf16 input, prepacked W^T): xwb = bf16(nsrc .* (H@W)) -------
__global__ __launch_bounds__(256) void k_xw_mfma(const unsigned* __restrict__ hb,
                                                 const int* __restrict__ out_cnt,
                                                 const unsigned* __restrict__ wTg,
                                                 unsigned* __restrict__ xwb, int N) {
    __shared__ unsigned wT[128 * 68];
    int t = threadIdx.x;
#pragma unroll
    for (int i = 0; i < 8; i++) {
        int idx = t + i * 256;
        int row = idx >> 4;
        int col = idx & 15;
        *(uint4*)&wT[row * 68 + col * 4] = ((const uint4*)wTg)[idx];
    }
    __syncthreads();
    int wave = t >> 6, lane = t & 63;
    int quad = lane >> 4, c = lane & 15;
    int m = blockIdx.x * 64 + wave * 16 + c;
    bool mv = m < N;
    f32x4 acc[8];
#pragma unroll
    for (int i = 0; i < 8; i++) acc[i] = (f32x4){0.f, 0.f, 0.f, 0.f};

#pragma unroll
    for (int ks = 0; ks < 4; ks++) {
        U16 av;
        if (mv) av.u = *(const uint4*)&hb[m * 64 + ks * 16 + quad * 4];
        else av.u = make_uint4(0, 0, 0, 0);
#pragma unroll
        for (int cb = 0; cb < 8; cb++) {
            U16 bv;
            bv.u = *(const uint4*)&wT[(cb * 16 + c) * 68 + ks * 16 + quad * 4];
            acc[cb] = __builtin_amdgcn_mfma_f32_16x16x32_bf16(av.b, bv.b, acc[cb], 0, 0, 0);
        }
    }
    int rowBase = blockIdx.x * 64 + wave * 16 + quad * 4;
#pragma unroll
    for (int r = 0; r < 4; r++) {
        int rowN = rowBase + r;
        float nrm = (rowN < N) ? rsqrtf((float)(out_cnt[rowN] + 1)) : 0.f;
#pragma unroll
        for (int cb = 0; cb < 8; cb++) {
            float v = acc[cb][r] * nrm;
            float vn = __shfl_xor(v, 1, 64);
            if (((c & 1) == 0) && rowN < N)
                xwb[rowN * 64 + cb * 8 + (c >> 1)] = pack2bf(v, vn);
        }
    }
}

// ---------------- pooling: weighted sum + max per graph ----------------
__device__ __forceinline__ int lower_bound(const int* a, int n, int key) {
    int lo = 0, hi = n;
    while (lo < hi) {
        int m = (lo + hi) >> 1;
        if (a[m] < key) lo = m + 1;
        else hi = m;
    }
    return lo;
}

__global__ __launch_bounds__(64) void k_pool(const unsigned* __restrict__ hb,
                                             const float* __restrict__ wg,
                                             const int* __restrict__ gids,
                                             float* __restrict__ out, int N) {
    int g = blockIdx.x >> 4;
    int part = blockIdx.x & 15;
    int t = threadIdx.x;
    int start = lower_bound(gids, N, g);
    int end = lower_bound(gids, N, g + 1);
    float2 sum = {0.f, 0.f}, mx = {0.f, 0.f};
    for (int n = start + part; n < end; n += 16) {
        float w = wg[n];
        float2 v = unpack2bf(hb[n * 64 + t]);
        sum.x += v.x * w;
        sum.y += v.y * w;
        mx.x = fmaxf(mx.x, v.x);
        mx.y = fmaxf(mx.y, v.y);
    }
    atomicAdd(&out[g * 256 + 2 * t], sum.x);
    atomicAdd(&out[g * 256 + 2 * t + 1], sum.y);
    atomicMax((int*)&out[g * 256 + 128 + 2 * t], __float_as_int(mx.x));
    atomicMax((int*)&out[g * 256 + 128 + 2 * t + 1], __float_as_int(mx.y));
}

extern "C" void kernel_launch(void* const* d_in, const int* in_sizes, int n_in,
                              void* d_out, int out_size, void* d_ws, size_t ws_size,
                              hipStream_t stream) {
    const float* node_feats = (const float*)d_in[0];
    const int* src = (const int*)d_in[1];
    const int* dst = (const int*)d_in[2];
    const int* gids = (const int*)d_in[3];
    const float* W1 = (const float*)d_in[4];
    const float* b1 = (const float*)d_in[5];
    const float* W2 = (const float*)d_in[6];
    const float* b2 = (const float*)d_in[7];
    const float* W3 = (const float*)d_in[8];
    const float* b3 = (const float*)d_in[9];
    const float* Wp = (const float*)d_in[10];
    const float* bp = (const float*)d_in[11];
    float* out = (float*)d_out;

    const int N = in_sizes[3];
    const int E = in_sizes[1];
    const int G = out_size / 256;
    const int NB = (N + 2047) >> 11;   // buckets of 2048 nodes (<= NBMAX)

    // ---- workspace layout (bytes) ----
    char* ws = (char*)d_ws;
    size_t o = 0;
    int* cntD = (int*)(ws + o);          o += NBMAX * 4;   // zeroed
    int* cntS = (int*)(ws + o);          o += NBMAX * 4;   // zeroed
    int* in_cnt = (int*)(ws + o);        o += (size_t)N * 4;   // zeroed; atomically built by k_mega
    int* out_cnt = (int*)(ws + o);       o += (size_t)N * 4;   // zeroed; atomically built by k_mega
    size_t zero_bytes = o;
    float* wg = (float*)(ws + o);        o += (size_t)N * 4;
    float* nsv = (float*)(ws + o);       o += (size_t)N * 4;   // rsqrt(out_deg+1), k_nrm (R14)
    o = (o + 15) & ~15ull;
    unsigned* wT1g = (unsigned*)(ws + o); o += 8192 * 4;
    unsigned* wT2g = (unsigned*)(ws + o); o += 8192 * 4;
    unsigned* wT3g = (unsigned*)(ws + o); o += 8192 * 4;
    unsigned* binD = (unsigned*)(ws + o); o += (size_t)NBMAX * BCAP * 4;
    unsigned short* binS = (unsigned short*)(ws + o); o += (size_t)NBMAX * BCAP * 2;
    o = (o + 15) & ~15ull;
    int* csr_pad = (int*)(ws + o);       o += (size_t)N * CAP * 4;
    unsigned* xwb = (unsigned*)(ws + o); o += (size_t)N * 64 * 4;
    unsigned* hb = (unsigned*)(ws + o);  o += (size_t)N * 64 * 4;
    (void)ws_size;

    (void)hipMemsetAsync(d_ws, 0, zero_bytes, stream);
    (void)hipMemsetAsync(d_out, 0, (size_t)out_size * 4, stream);

    int binGrid = (E + 1023) / 1024;
    int mmGrid = (N + 63) / 64;
    int aggGrid = (N + 15) / 16;      // 4 nodes/wave, 4 waves/block
    int nrmGrid = (N + 1023) / 1024;

    // Phase 1: bucket edges (replicated-counter) + W1/W2/W3 bf16-transpose prepack (3 tail blocks)
    k_bin<<<binGrid + 3, 256, 0, stream>>>(src, dst, E, binD, binS, cntD, cntS, NB, binGrid,
                                           W1, W2, W3, wT1g, wT2g, wT3g);
    // Phase 2: CSR-from-buckets (CSPLIT-way) + out-degree histogram + layer-1 MFMA GEMM
    k_mega<<<2 * NB * CSPLIT + mmGrid, 256, 0, stream>>>(binD, binS, cntD, cntS, in_cnt,
                                                         out_cnt, csr_pad, node_feats,
                                                         wT1g, xwb, N, NB);
    // nsv = rsqrt(out_deg+1) once (L2-hot table; do NOT inline into agg1 — R18 regression)
    k_nrm<<<nrmGrid, 256, 0, stream>>>(out_cnt, nsv, N);
    // layer-1 aggregation (applies nsrc per source inline): xwb -> h1 (hb)
    k_agg1<<<aggGrid, 256, 0, stream>>>((const uint4*)xwb, in_cnt, csr_pad, nsv, b1,
                                        (uint4*)hb, N);
    // layer 2
    k_xw_mfma<<<mmGrid, 256, 0, stream>>>(hb, out_cnt, wT2g, xwb, N);
    k_agg<<<aggGrid, 256, 0, stream>>>((const uint4*)xwb, in_cnt, csr_pad, b2,
                                       (uint4*)hb, N);
    // layer 3 (+ fused sigmoid gate)
    k_xw_mfma<<<mmGrid, 256, 0, stream>>>(hb, out_cnt, wT3g, xwb, N);
    k_agg_gate<<<aggGrid, 256, 0, stream>>>((const uint4*)xwb, in_cnt, csr_pad, b3,
                                            (uint4*)hb, Wp, bp, wg, N);
    // pooling
    k_pool<<<G * 16, 64, 0, stream>>>(hb, wg, gids, out, N);
}